// Round 4
// baseline (3698.100 us; speedup 1.0000x reference)
//
#include <hip/hip_runtime.h>
#include <stdint.h>

// ---------------- problem constants ----------------
#define B_   32
#define T_   256
#define H_   256      // per-direction hidden
#define DB_  768      // input dim
#define DL_  512      // 2*H

// ---------------- workspace layout (bytes) — total 24.07 MB ----------------
#define OFF_DTYPE 0u                          // int: 1 = inputs are bf16, 0 = f32
#define OFF_FLAGS 256u                        // [2 dir][256 t] u32 barrier counters
#define OFF_HBUF  4096u                       // [2 parity][2 dir][32 b][256 k] bf16 = 64 KB
#define OFF_XZ    69632u                      // swizzled xz (ONE dir at a time): [4w][4wave][256t][2048] bf16 = 16 MB
#define OFF_HIST  (OFF_XZ + 16777216u)        // h [32 b][256 t][512 d] bf16 = 8 MB   (end: 25,235,456 B)
// ---- aliased into the xz region (xz dead after the two rec_k launches) ----
#define OFF_CTX   OFF_XZ                      // context [32][256][512] bf16 = 8 MB
#define OFF_WATT  (OFF_XZ + 8388608u)         // attn weights [32][256 q][256 k] bf16 = 4 MB
#define OFF_SQ    (OFF_XZ + 12582912u)        // [8192][10] f32 = 320 KB
#define OFF_SK    (OFF_SQ + 327680u)          // [8192][10] f32 = 320 KB

typedef __attribute__((ext_vector_type(8))) short bf16x8;
typedef __attribute__((ext_vector_type(4))) float f32x4;
typedef unsigned short ushort_t;

__device__ __forceinline__ float b2f(ushort_t u){ union{float f; uint32_t i;} v; v.i=((uint32_t)u)<<16; return v.f; }
__device__ __forceinline__ ushort_t f2b(float f){
  union{float ff; uint32_t i;} v; v.ff=f;
  uint32_t r = v.i + 0x7fffu + ((v.i>>16)&1u);
  return (ushort_t)(r>>16);
}
__device__ __forceinline__ float sig_f(float x){ return 1.f/(1.f+__expf(-x)); }
__device__ __forceinline__ float tanh_f(float x){ return 1.f - 2.f/(1.f+__expf(2.f*x)); }

// dual-dtype loads: idx is an ELEMENT index (multiple of 8 for load8)
__device__ __forceinline__ bf16x8 load8(const ushort_t* p, size_t idx, int isbf){
  if (isbf) return *(const bf16x8*)(p + idx);
  const float* f = (const float*)p;
  bf16x8 r;
  #pragma unroll
  for (int i=0;i<8;++i) r[i] = (short)f2b(f[idx+i]);
  return r;
}
__device__ __forceinline__ float loadS(const ushort_t* p, size_t idx, int isbf){
  return isbf ? b2f(p[idx]) : ((const float*)p)[idx];
}

// =====================================================================
// dtype probe: bf16-packed x -> low u16 of each u32 is a N(0,1) bf16
// sample (exp field in [118,130] w.p. ~0.997). f32 x -> low u16 is random
// mantissa bits (~5% in range). Vote over 1024 words.
// =====================================================================
__global__ void detect_k(const uint32_t* __restrict__ x, char* __restrict__ ws){
  __shared__ int cnt;
  if (threadIdx.x == 0) cnt = 0;
  __syncthreads();
  int local = 0;
  #pragma unroll
  for (int i=0;i<4;++i){
    uint32_t w = x[threadIdx.x*4 + i];
    uint32_t lo = w & 0xFFFFu;
    int e = (int)((lo >> 7) & 0xFFu);
    if (e >= 118 && e <= 130) local++;
  }
  atomicAdd(&cnt, local);
  __syncthreads();
  if (threadIdx.x == 0) *(int*)(ws + OFF_DTYPE) = (cnt > 512) ? 1 : 0;
}

// =====================================================================
// Generic 128x128-tile bf16 MFMA GEMM:  C[m][n] = sum_k A[m][k]*B[n][k]
// MODE 0: +bias[n], scatter into swizzled xz (time-reversed for dir==1).
// MODE 2: A = concat(h,ctx) (k<512 -> A0, k>=512 -> A2), +bias,
//         store to d_out in the HARNESS dtype (f32 if dtf==0, else bf16).
// MODE 3: B is ROW-MAJOR [K][N] (hist per batch); staged untransposed,
//         B-fragments gathered from LDS columns. Plain bf16 store, batched z.
// aIn/bIn: operand may be a raw input (dual-dtype); ws operands pass 0.
// =====================================================================
template<int MODE>
__global__ __launch_bounds__(256,2) void gemm_k(
    const ushort_t* __restrict__ A0, const ushort_t* __restrict__ A2,
    const ushort_t* __restrict__ Bm, const ushort_t* __restrict__ bias,
    ushort_t* __restrict__ Cout, char* __restrict__ ws,
    int lda, int ldb, int K, int dir, int aIn, int bIn,
    long aOffZ, long bOffZ, long cOffZ)
{
  __shared__ ushort_t As[8192];   // [128 m][64 k], chunk-XOR-swizzled
  __shared__ ushort_t Bs[8192];   // MODE!=3: [128 n][64 k] swizzled; MODE 3: [64 k][128 n]
  const int dtf = *(const int*)(ws + OFF_DTYPE);
  const int aBF = aIn ? dtf : 1;
  const int bBF = bIn ? dtf : 1;
  const int tid = threadIdx.x;
  const int l  = tid & 63, wv = tid >> 6;
  const int lc = l & 15,  lh = l >> 4;
  const int m0 = blockIdx.x * 128, n0 = blockIdx.y * 128;
  const int z  = blockIdx.z;
  const ushort_t* Abase = A0 + (size_t)z * aOffZ;
  const ushort_t* Bbase = Bm + (size_t)z * bOffZ;
  const int srow = tid >> 3;   // 0..31 staging row within pass
  const int sch  = tid & 7;    // staging 16B chunk

  f32x4 acc[4][4];
  #pragma unroll
  for (int i=0;i<4;++i)
    #pragma unroll
    for (int j=0;j<4;++j) acc[i][j] = (f32x4){0.f,0.f,0.f,0.f};

  bf16x8 ra[4], rb[4];
  #pragma unroll
  for (int p=0;p<4;++p){
    int row = p*32 + srow;
    int kk  = (sch ^ (row & 7)) * 8;
    ra[p] = load8(Abase, (size_t)(m0+row)*lda + kk, aBF);
    if (MODE==3){
      int q = p*256 + tid, kr = q>>4, c = q&15;
      rb[p] = load8(Bbase, (size_t)kr*ldb + n0 + c*8, 1);
    } else {
      rb[p] = load8(Bbase, (size_t)(n0+row)*ldb + kk, bBF);
    }
  }

  const int mo = (wv&1)*64, no = (wv>>1)*64;

  for (int k0 = 0; k0 < K; k0 += 64) {
    #pragma unroll
    for (int p=0;p<4;++p){
      int row = p*32 + srow;
      *(bf16x8*)(&As[row*64 + sch*8]) = ra[p];
      if (MODE==3){
        int q = p*256 + tid, kr = q>>4, c = q&15;
        *(bf16x8*)(&Bs[kr*128 + c*8]) = rb[p];
      } else {
        *(bf16x8*)(&Bs[row*64 + sch*8]) = rb[p];
      }
    }
    __syncthreads();
    int k1 = k0 + 64;
    if (k1 < K) {
      #pragma unroll
      for (int p=0;p<4;++p){
        int row = p*32 + srow;
        int kk  = k1 + (sch ^ (row & 7)) * 8;
        if (MODE==2 && k1 >= 512)
          ra[p] = load8(A2, (size_t)(m0+row)*512 + (kk - 512), 1);
        else
          ra[p] = load8(Abase, (size_t)(m0+row)*lda + kk, aBF);
        if (MODE==3){
          int q = p*256 + tid, kr = q>>4, c = q&15;
          rb[p] = load8(Bbase, (size_t)(k1+kr)*ldb + n0 + c*8, 1);
        } else {
          rb[p] = load8(Bbase, (size_t)(n0+row)*ldb + kk, bBF);
        }
      }
    }
    #pragma unroll
    for (int kc=0;kc<2;++kc){
      bf16x8 af[4], bfv[4];
      #pragma unroll
      for (int it=0;it<4;++it){
        int m = mo + it*16 + lc;
        int gc = kc*4 + lh;
        af[it]  = *(const bf16x8*)(&As[m*64 + ((gc ^ (m&7))*8)]);
        int n = no + it*16 + lc;
        if (MODE==3){
          #pragma unroll
          for (int j=0;j<8;++j) bfv[it][j] = (short)Bs[(kc*32 + lh*8 + j)*128 + n];
        } else {
          bfv[it] = *(const bf16x8*)(&Bs[n*64 + ((gc ^ (n&7))*8)]);
        }
      }
      #pragma unroll
      for (int mt=0;mt<4;++mt)
        #pragma unroll
        for (int nt=0;nt<4;++nt)
          acc[mt][nt] = __builtin_amdgcn_mfma_f32_16x16x32_bf16(af[mt], bfv[nt], acc[mt][nt], 0,0,0);
    }
    __syncthreads();
  }

  ushort_t* xzsw = (ushort_t*)(ws + OFF_XZ);
  #pragma unroll
  for (int mt=0;mt<4;++mt){
    #pragma unroll
    for (int nt=0;nt<4;++nt){
      #pragma unroll
      for (int r=0;r<4;++r){
        int m = m0 + mo + mt*16 + lh*4 + r;   // C/D layout: row=(l>>4)*4+reg
        int n = n0 + no + nt*16 + lc;          //             col=l&15
        float v = acc[mt][nt][r];
        if (MODE==0){
          v += loadS(bias, n, bBF);
          int b = m >> 8, t = m & 255;
          int ts = dir ? (255 - t) : t;        // backward dir consumes reversed time
          int q = n >> 8, jm = n & 255;
          int w = jm >> 6, jj = jm & 63, wvv = jj >> 4, colj = jj & 15;
          int lane = ((b >> 2) & 3)*16 + colj;
          int idx  = (b >> 4)*16 + q*4 + (b & 3);
          size_t e = (((size_t)(w*4 + wvv)*256 + ts)*2048) + (size_t)lane*32 + idx;
          xzsw[e] = f2b(v);
        } else if (MODE==3){
          Cout[(size_t)z*cOffZ + (size_t)m*DL_ + n] = f2b(v);
        } else {
          v += loadS(bias, n, bBF);
          if (dtf) Cout[(size_t)m*DL_ + n] = f2b(v);          // harness out = bf16
          else     ((float*)Cout)[(size_t)m*DL_ + n] = v;     // harness out = f32
        }
      }
    }
  }
}

// =====================================================================
// Persistent single-direction LSTM recurrence (dir d passed in).
// 4 blocks = hidden-quarters. 256 threads = 4 waves. Whh B-fragments
// persistent in VGPRs; h(t-1) via double-buffered global hbuf +
// device-scope flag barrier across the 4 blocks.
// =====================================================================
__global__ __launch_bounds__(256,1) void rec_k(
    const ushort_t* __restrict__ Whh_f, const ushort_t* __restrict__ Whh_b,
    char* __restrict__ ws, int d)
{
  const int w = blockIdx.x;
  const int tid = threadIdx.x;
  const int wv = tid >> 6, l = tid & 63;
  const int lc = l & 15, lh = l >> 4;
  const int dtf = *(const int*)(ws + OFF_DTYPE);

  ushort_t* hbuf = (ushort_t*)(ws + OFF_HBUF);
  const ushort_t* xz = (const ushort_t*)(ws + OFF_XZ);
  ushort_t* hist  = (ushort_t*)(ws + OFF_HIST);
  const ushort_t* Whh = d ? Whh_b : Whh_f;

  const int jj = 64*w + 16*wv + lc;   // hidden unit this lane's B-frag column maps to

  bf16x8 wf[4][8];                    // [gate][k-chunk], persistent in VGPRs
  #pragma unroll
  for (int nt=0;nt<4;++nt)
    #pragma unroll
    for (int kc=0;kc<8;++kc)
      wf[nt][kc] = load8(Whh, (size_t)(nt*256 + jj)*256 + kc*32 + lh*8, dtf);

  float cst[2][4];
  #pragma unroll
  for (int i=0;i<2;++i){ cst[i][0]=0.f; cst[i][1]=0.f; cst[i][2]=0.f; cst[i][3]=0.f; }

  const ushort_t* xzb = xz + ((size_t)(w*4+wv)*256)*2048 + (size_t)l*32;

  for (int t=0; t<T_; ++t){
    bf16x8 xzv[4];
    #pragma unroll
    for (int i=0;i<4;++i) xzv[i] = *(const bf16x8*)(xzb + (size_t)t*2048 + i*8);

    f32x4 acc[2][4];
    #pragma unroll
    for (int i=0;i<2;++i)
      #pragma unroll
      for (int j=0;j<4;++j) acc[i][j] = (f32x4){0.f,0.f,0.f,0.f};

    if (t > 0){
      if (tid == 0){
        uint32_t* fl = (uint32_t*)(ws + OFF_FLAGS) + d*T_ + (t-1);
        while (__hip_atomic_load(fl, __ATOMIC_ACQUIRE, __HIP_MEMORY_SCOPE_AGENT) < 4u)
          __builtin_amdgcn_s_sleep(1);
      }
      __syncthreads();
      const ushort_t* hb = hbuf + (size_t)(((t-1)&1)*2 + d)*(B_*H_);
      #pragma unroll
      for (int kc=0;kc<8;++kc){
        bf16x8 a0 = *(const bf16x8*)(hb + (size_t)lc*256      + kc*32 + lh*8);
        bf16x8 a1 = *(const bf16x8*)(hb + (size_t)(16+lc)*256 + kc*32 + lh*8);
        #pragma unroll
        for (int nt=0;nt<4;++nt){
          acc[0][nt] = __builtin_amdgcn_mfma_f32_16x16x32_bf16(a0, wf[nt][kc], acc[0][nt], 0,0,0);
          acc[1][nt] = __builtin_amdgcn_mfma_f32_16x16x32_bf16(a1, wf[nt][kc], acc[1][nt], 0,0,0);
        }
      }
    }

    const int ts = d ? (255 - t) : t;
    ushort_t* hb_out = hbuf + (size_t)((t&1)*2 + d)*(B_*H_);
    #pragma unroll
    for (int mt=0;mt<2;++mt){
      #pragma unroll
      for (int r=0;r<4;++r){
        int fi = mt*16 + r;
        float zi = acc[mt][0][r] + b2f((ushort_t)xzv[(fi+0 )>>3][(fi+0 )&7]);
        float zf = acc[mt][1][r] + b2f((ushort_t)xzv[(fi+4 )>>3][(fi+4 )&7]);
        float zg = acc[mt][2][r] + b2f((ushort_t)xzv[(fi+8 )>>3][(fi+8 )&7]);
        float zo = acc[mt][3][r] + b2f((ushort_t)xzv[(fi+12)>>3][(fi+12)&7]);
        float ig = sig_f(zi), fg = sig_f(zf), gg = tanh_f(zg), og = sig_f(zo);
        float c = fg * cst[mt][r] + ig * gg;
        cst[mt][r] = c;
        float h = og * tanh_f(c);
        ushort_t h16 = f2b(h);
        int b = mt*16 + lh*4 + r;
        hb_out[(size_t)b*256 + jj] = h16;
        hist [((size_t)(b*256 + ts))*512 + d*256 + jj] = h16;
      }
    }
    __threadfence();
    __syncthreads();
    if (tid == 0){
      uint32_t* fl = (uint32_t*)(ws + OFF_FLAGS) + d*T_ + t;
      __hip_atomic_fetch_add(fl, 1u, __ATOMIC_RELEASE, __HIP_MEMORY_SCOPE_AGENT);
    }
  }
}

// =====================================================================
// C1: sq[m][x] = h[m]·W1[x][0:512], sk[m][x] = h[m]·W1[x][512:1024]
// =====================================================================
__global__ __launch_bounds__(256) void c1_k(char* __restrict__ ws, const ushort_t* __restrict__ W1)
{
  const ushort_t* hist = (const ushort_t*)(ws + OFF_HIST);
  float* sq = (float*)(ws + OFF_SQ);
  float* sk = (float*)(ws + OFF_SK);
  const int dtf = *(const int*)(ws + OFF_DTYPE);
  int tid = threadIdx.x; int wv = tid>>6, l = tid&63;
  int row = blockIdx.x*4 + wv;
  bf16x8 hv = *(const bf16x8*)(hist + (size_t)row*512 + l*8);
  float hf[8];
  #pragma unroll
  for (int i=0;i<8;++i) hf[i] = b2f((ushort_t)hv[i]);
  #pragma unroll
  for (int x=0;x<10;++x){
    bf16x8 qv = load8(W1, (size_t)x*1024 + l*8, dtf);
    bf16x8 kv = load8(W1, (size_t)x*1024 + 512 + l*8, dtf);
    float pq=0.f, pk=0.f;
    #pragma unroll
    for (int i=0;i<8;++i){ pq += hf[i]*b2f((ushort_t)qv[i]); pk += hf[i]*b2f((ushort_t)kv[i]); }
    #pragma unroll
    for (int off=32; off>0; off>>=1){ pq += __shfl_xor(pq, off, 64); pk += __shfl_xor(pk, off, 64); }
    if (l == 0){ sq[row*10 + x] = pq; sk[row*10 + x] = pk; }
  }
}

// =====================================================================
// C2: a[b,q,k] = sum_x tanh(sq+sk)*W2[x]; masked softmax over k -> bf16 watt
// =====================================================================
__global__ __launch_bounds__(256) void c2_k(char* __restrict__ ws, const ushort_t* __restrict__ W2,
                                            const ushort_t* __restrict__ mask)
{
  const float* sq = (const float*)(ws + OFF_SQ);
  const float* sk = (const float*)(ws + OFF_SK);
  ushort_t* watt = (ushort_t*)(ws + OFF_WATT);
  const int dtf = *(const int*)(ws + OFF_DTYPE);
  int tid = threadIdx.x; int wv = tid>>6, l = tid&63;
  int bq = blockIdx.x*4 + wv;
  int b  = bq >> 8;
  float sqv[10], w2v[10];
  #pragma unroll
  for (int x=0;x<10;++x){ sqv[x] = sq[(size_t)bq*10+x]; w2v[x] = loadS(W2, x, dtf); }
  float a[4];
  #pragma unroll
  for (int kk=0;kk<4;++kk){
    int k = kk*64 + l;
    const float* skp = sk + ((size_t)b*256 + k)*10;
    float s = 0.f;
    #pragma unroll
    for (int x=0;x<10;++x) s += tanh_f(sqv[x] + skp[x]) * w2v[x];
    float mval = loadS(mask, (size_t)b*256 + k, dtf);
    a[kk] = (mval == 0.f) ? -1e30f : s;
  }
  float mx = fmaxf(fmaxf(a[0],a[1]), fmaxf(a[2],a[3]));
  #pragma unroll
  for (int off=32; off>0; off>>=1) mx = fmaxf(mx, __shfl_xor(mx, off, 64));
  float e[4], ssum=0.f;
  #pragma unroll
  for (int kk=0;kk<4;++kk){ e[kk] = __expf(a[kk]-mx); ssum += e[kk]; }
  #pragma unroll
  for (int off=32; off>0; off>>=1) ssum += __shfl_xor(ssum, off, 64);
  float inv = 1.f/ssum;
  #pragma unroll
  for (int kk=0;kk<4;++kk) watt[(size_t)bq*256 + kk*64 + l] = f2b(e[kk]*inv);
}

// =====================================================================
extern "C" void kernel_launch(void* const* d_in, const int* in_sizes, int n_in,
                              void* d_out, int out_size, void* d_ws, size_t ws_size,
                              hipStream_t stream)
{
  const ushort_t* x     = (const ushort_t*)d_in[0];
  const ushort_t* mask  = (const ushort_t*)d_in[1];
  const ushort_t* Wih_f = (const ushort_t*)d_in[2];
  const ushort_t* Whh_f = (const ushort_t*)d_in[3];
  const ushort_t* b_f   = (const ushort_t*)d_in[4];
  const ushort_t* Wih_b = (const ushort_t*)d_in[5];
  const ushort_t* Whh_b = (const ushort_t*)d_in[6];
  const ushort_t* b_b   = (const ushort_t*)d_in[7];
  const ushort_t* W1    = (const ushort_t*)d_in[8];
  const ushort_t* W2    = (const ushort_t*)d_in[9];
  const ushort_t* W3    = (const ushort_t*)d_in[10];
  const ushort_t* b3    = (const ushort_t*)d_in[11];
  ushort_t* out = (ushort_t*)d_out;
  char* ws = (char*)d_ws;

  hipMemsetAsync(ws, 0, 4096, stream);           // dtype flag + barrier flags
  detect_k<<<dim3(1), dim3(256), 0, stream>>>((const uint32_t*)d_in[0], ws);

  dim3 blk(256);
  // forward dir: xz -> recurrence
  gemm_k<0><<<dim3(64,8,1), blk, 0, stream>>>(x, nullptr, Wih_f, b_f, nullptr, ws,
                                              DB_, DB_, DB_, 0, 1, 1, 0,0,0);
  rec_k<<<dim3(4), blk, 0, stream>>>(Whh_f, Whh_b, ws, 0);
  // backward dir: xz (reuses buffer) -> recurrence
  gemm_k<0><<<dim3(64,8,1), blk, 0, stream>>>(x, nullptr, Wih_b, b_b, nullptr, ws,
                                              DB_, DB_, DB_, 1, 1, 1, 0,0,0);
  rec_k<<<dim3(4), blk, 0, stream>>>(Whh_f, Whh_b, ws, 1);
  // attention
  c1_k<<<dim3(2048), blk, 0, stream>>>(ws, W1);
  c2_k<<<dim3(2048), blk, 0, stream>>>(ws, W2, mask);
  // context = watt @ h (per batch), B row-major from hist
  gemm_k<3><<<dim3(2,4,32), blk, 0, stream>>>((ushort_t*)(ws+OFF_WATT), nullptr,
                                              (ushort_t*)(ws+OFF_HIST), nullptr,
                                              (ushort_t*)(ws+OFF_CTX), ws,
                                              256, 512, 256, 0, 0, 0,
                                              65536L, 131072L, 131072L);
  // y = concat(h, ctx) @ W3^T + b3 -> d_out (dtype-matched store)
  gemm_k<2><<<dim3(64,4,1), blk, 0, stream>>>((ushort_t*)(ws+OFF_HIST), (ushort_t*)(ws+OFF_CTX),
                                              W3, b3, out, ws,
                                              512, 1024, 1024, 0, 0, 1, 0,0,0);
}

// Round 5
// 3200.576 us; speedup vs baseline: 1.1554x; 1.1554x over previous
//
#include <hip/hip_runtime.h>
#include <stdint.h>

// ---------------- problem constants ----------------
#define B_   32
#define T_   256
#define H_   256      // per-direction hidden
#define DB_  768      // input dim
#define DL_  512      // 2*H

// ---------------- workspace layout (bytes) ----------------
// common prefix:
#define OFF_DTYPE 0u                          // int: 1 = inputs bf16, 0 = f32
#define OFF_FLAGS 256u                        // [2 dir][256 t] u32 flag counters (target 16)
#define OFF_HBUF  4096u                       // [2 parity][2 dir][32 b][256 k] bf16 = 64 KB
#define OFF_XZ    69632u                      // swizzled xz, per-dir stride 8M elems (16 MB)
// concurrent layout: xz = 32 MB (both dirs), hist after -> needs 42,012,672 B
// sequential layout: xz = 16 MB (one dir at a time), hist after -> 25,235,456 B
#define XZ_DIR_ELEMS 8388608u
#define NEED_CONC (OFF_XZ + 2u*16777216u + 8388608u)
// ---- aliased into the xz region (xz dead after rec) — same in both layouts ----
#define OFF_CTX   OFF_XZ                      // context [32][256][512] bf16 = 8 MB
#define OFF_WATT  (OFF_XZ + 8388608u)         // attn weights [32][256][256] bf16 = 4 MB
#define OFF_SQ    (OFF_XZ + 12582912u)        // [8192][10] f32
#define OFF_SK    (OFF_SQ + 327680u)          // [8192][10] f32

typedef __attribute__((ext_vector_type(8))) short bf16x8;
typedef __attribute__((ext_vector_type(4))) float f32x4;
typedef __attribute__((ext_vector_type(4))) uint32_t u32x4;
typedef unsigned short ushort_t;

__device__ __forceinline__ float b2f(ushort_t u){ union{float f; uint32_t i;} v; v.i=((uint32_t)u)<<16; return v.f; }
__device__ __forceinline__ ushort_t f2b(float f){
  union{float ff; uint32_t i;} v; v.ff=f;
  uint32_t r = v.i + 0x7fffu + ((v.i>>16)&1u);
  return (ushort_t)(r>>16);
}
__device__ __forceinline__ float sig_f(float x){ return 1.f/(1.f+__expf(-x)); }
__device__ __forceinline__ float tanh_f(float x){ return 1.f - 2.f/(1.f+__expf(2.f*x)); }

__device__ __forceinline__ bf16x8 load8(const ushort_t* p, size_t idx, int isbf){
  if (isbf) return *(const bf16x8*)(p + idx);
  const float* f = (const float*)p;
  bf16x8 r;
  #pragma unroll
  for (int i=0;i<8;++i) r[i] = (short)f2b(f[idx+i]);
  return r;
}
__device__ __forceinline__ float loadS(const ushort_t* p, size_t idx, int isbf){
  return isbf ? b2f(p[idx]) : ((const float*)p)[idx];
}

// =====================================================================
// dtype probe (R3-verified): votes f32 vs bf16 from exponent stats.
// =====================================================================
__global__ void detect_k(const uint32_t* __restrict__ x, char* __restrict__ ws){
  __shared__ int cnt;
  if (threadIdx.x == 0) cnt = 0;
  __syncthreads();
  int local = 0;
  #pragma unroll
  for (int i=0;i<4;++i){
    uint32_t w = x[threadIdx.x*4 + i];
    uint32_t lo = w & 0xFFFFu;
    int e = (int)((lo >> 7) & 0xFFu);
    if (e >= 118 && e <= 130) local++;
  }
  atomicAdd(&cnt, local);
  __syncthreads();
  if (threadIdx.x == 0) *(int*)(ws + OFF_DTYPE) = (cnt > 512) ? 1 : 0;
}

// =====================================================================
// Generic 128x128-tile bf16 MFMA GEMM (unchanged from R4-pass version).
// MODE 0: +bias[n], scatter into swizzled xz (+cOffZ dir offset).
// MODE 2: A=concat(h,ctx); +bias; store d_out in harness dtype.
// MODE 3: B row-major [K][N]; LDS column gather; bf16 store, batched z.
// =====================================================================
template<int MODE>
__global__ __launch_bounds__(256,2) void gemm_k(
    const ushort_t* __restrict__ A0, const ushort_t* __restrict__ A2,
    const ushort_t* __restrict__ Bm, const ushort_t* __restrict__ bias,
    ushort_t* __restrict__ Cout, char* __restrict__ ws,
    int lda, int ldb, int K, int dir, int aIn, int bIn,
    long aOffZ, long bOffZ, long cOffZ)
{
  __shared__ ushort_t As[8192];
  __shared__ ushort_t Bs[8192];
  const int dtf = *(const int*)(ws + OFF_DTYPE);
  const int aBF = aIn ? dtf : 1;
  const int bBF = bIn ? dtf : 1;
  const int tid = threadIdx.x;
  const int l  = tid & 63, wv = tid >> 6;
  const int lc = l & 15,  lh = l >> 4;
  const int m0 = blockIdx.x * 128, n0 = blockIdx.y * 128;
  const int z  = blockIdx.z;
  const ushort_t* Abase = A0 + (size_t)z * aOffZ;
  const ushort_t* Bbase = Bm + (size_t)z * bOffZ;
  const int srow = tid >> 3;
  const int sch  = tid & 7;

  f32x4 acc[4][4];
  #pragma unroll
  for (int i=0;i<4;++i)
    #pragma unroll
    for (int j=0;j<4;++j) acc[i][j] = (f32x4){0.f,0.f,0.f,0.f};

  bf16x8 ra[4], rb[4];
  #pragma unroll
  for (int p=0;p<4;++p){
    int row = p*32 + srow;
    int kk  = (sch ^ (row & 7)) * 8;
    ra[p] = load8(Abase, (size_t)(m0+row)*lda + kk, aBF);
    if (MODE==3){
      int q = p*256 + tid, kr = q>>4, c = q&15;
      rb[p] = load8(Bbase, (size_t)kr*ldb + n0 + c*8, 1);
    } else {
      rb[p] = load8(Bbase, (size_t)(n0+row)*ldb + kk, bBF);
    }
  }

  const int mo = (wv&1)*64, no = (wv>>1)*64;

  for (int k0 = 0; k0 < K; k0 += 64) {
    #pragma unroll
    for (int p=0;p<4;++p){
      int row = p*32 + srow;
      *(bf16x8*)(&As[row*64 + sch*8]) = ra[p];
      if (MODE==3){
        int q = p*256 + tid, kr = q>>4, c = q&15;
        *(bf16x8*)(&Bs[kr*128 + c*8]) = rb[p];
      } else {
        *(bf16x8*)(&Bs[row*64 + sch*8]) = rb[p];
      }
    }
    __syncthreads();
    int k1 = k0 + 64;
    if (k1 < K) {
      #pragma unroll
      for (int p=0;p<4;++p){
        int row = p*32 + srow;
        int kk  = k1 + (sch ^ (row & 7)) * 8;
        if (MODE==2 && k1 >= 512)
          ra[p] = load8(A2, (size_t)(m0+row)*512 + (kk - 512), 1);
        else
          ra[p] = load8(Abase, (size_t)(m0+row)*lda + kk, aBF);
        if (MODE==3){
          int q = p*256 + tid, kr = q>>4, c = q&15;
          rb[p] = load8(Bbase, (size_t)(k1+kr)*ldb + n0 + c*8, 1);
        } else {
          rb[p] = load8(Bbase, (size_t)(n0+row)*ldb + kk, bBF);
        }
      }
    }
    #pragma unroll
    for (int kc=0;kc<2;++kc){
      bf16x8 af[4], bfv[4];
      #pragma unroll
      for (int it=0;it<4;++it){
        int m = mo + it*16 + lc;
        int gc = kc*4 + lh;
        af[it]  = *(const bf16x8*)(&As[m*64 + ((gc ^ (m&7))*8)]);
        int n = no + it*16 + lc;
        if (MODE==3){
          #pragma unroll
          for (int j=0;j<8;++j) bfv[it][j] = (short)Bs[(kc*32 + lh*8 + j)*128 + n];
        } else {
          bfv[it] = *(const bf16x8*)(&Bs[n*64 + ((gc ^ (n&7))*8)]);
        }
      }
      #pragma unroll
      for (int mt=0;mt<4;++mt)
        #pragma unroll
        for (int nt=0;nt<4;++nt)
          acc[mt][nt] = __builtin_amdgcn_mfma_f32_16x16x32_bf16(af[mt], bfv[nt], acc[mt][nt], 0,0,0);
    }
    __syncthreads();
  }

  ushort_t* xzsw = (ushort_t*)(ws + OFF_XZ);
  #pragma unroll
  for (int mt=0;mt<4;++mt){
    #pragma unroll
    for (int nt=0;nt<4;++nt){
      #pragma unroll
      for (int r=0;r<4;++r){
        int m = m0 + mo + mt*16 + lh*4 + r;
        int n = n0 + no + nt*16 + lc;
        float v = acc[mt][nt][r];
        if (MODE==0){
          v += loadS(bias, n, bBF);
          int b = m >> 8, t = m & 255;
          int ts = dir ? (255 - t) : t;
          int q = n >> 8, jm = n & 255;
          int w = jm >> 6, jj = jm & 63, wvv = jj >> 4, colj = jj & 15;
          int lane = ((b >> 2) & 3)*16 + colj;
          int idx  = (b >> 4)*16 + q*4 + (b & 3);
          size_t e = (((size_t)(w*4 + wvv)*256 + ts)*2048) + (size_t)lane*32 + idx;
          xzsw[e + (size_t)cOffZ] = f2b(v);
        } else if (MODE==3){
          Cout[(size_t)z*cOffZ + (size_t)m*DL_ + n] = f2b(v);
        } else {
          v += loadS(bias, n, bBF);
          if (dtf) Cout[(size_t)m*DL_ + n] = f2b(v);
          else     ((float*)Cout)[(size_t)m*DL_ + n] = v;
        }
      }
    }
  }
}

// =====================================================================
// Persistent BiLSTM recurrence — fence-free LLC handoff.
// grid=8 (concurrent: d=blockIdx>>2) or grid=4 (sequential: d=dParam).
// Per wave: Whh B-frags resident in VGPRs; per step:
//   poll flag[d][t-1]==16 (relaxed agent) -> 64 relaxed-agent u32 loads of
//   h(t-1) (LLC) -> 64 MFMAs -> cell -> pack u32 via shfl_xor ->
//   relaxed-agent u32 stores -> s_waitcnt vmcnt(0) -> flag[d][t] += 1.
// No __syncthreads, no fences, no cache invalidates (xz stays L2-hot).
// =====================================================================
__global__ __launch_bounds__(256,1) void rec_k(
    const ushort_t* __restrict__ Whh_f, const ushort_t* __restrict__ Whh_b,
    char* __restrict__ ws, ushort_t* __restrict__ hist,
    int dParam, long xzDirStride)
{
  const int d = (gridDim.x == 8) ? (int)(blockIdx.x >> 2) : dParam;
  const int w = blockIdx.x & 3;
  const int tid = threadIdx.x;
  const int wv = tid >> 6, l = tid & 63;
  const int lc = l & 15, lh = l >> 4;
  const int dtf = *(const int*)(ws + OFF_DTYPE);

  uint32_t* flags = (uint32_t*)(ws + OFF_FLAGS);
  uint32_t* hbuf  = (uint32_t*)(ws + OFF_HBUF);     // u32-packed bf16 pairs
  const ushort_t* xz = (const ushort_t*)(ws + OFF_XZ) + (size_t)d * xzDirStride;
  const ushort_t* Whh = d ? Whh_b : Whh_f;

  const int jj = 64*w + 16*wv + lc;

  bf16x8 wf[4][8];                    // [gate][k-chunk], persistent in VGPRs
  #pragma unroll
  for (int nt=0;nt<4;++nt)
    #pragma unroll
    for (int kc=0;kc<8;++kc)
      wf[nt][kc] = load8(Whh, (size_t)(nt*256 + jj)*256 + kc*32 + lh*8, dtf);

  float cst[2][4];
  #pragma unroll
  for (int i=0;i<2;++i){ cst[i][0]=0.f; cst[i][1]=0.f; cst[i][2]=0.f; cst[i][3]=0.f; }

  const ushort_t* xzb = xz + ((size_t)(w*4+wv)*256)*2048 + (size_t)l*32;

  for (int t=0; t<T_; ++t){
    bf16x8 xzv[4];
    #pragma unroll
    for (int i=0;i<4;++i) xzv[i] = *(const bf16x8*)(xzb + (size_t)t*2048 + i*8);

    f32x4 acc[2][4];
    #pragma unroll
    for (int i=0;i<2;++i)
      #pragma unroll
      for (int j=0;j<4;++j) acc[i][j] = (f32x4){0.f,0.f,0.f,0.f};

    if (t > 0){
      const uint32_t* fl = flags + d*T_ + (t-1);
      while (__hip_atomic_load(fl, __ATOMIC_RELAXED, __HIP_MEMORY_SCOPE_AGENT) < 16u)
        __builtin_amdgcn_s_sleep(1);

      const uint32_t* hb = hbuf + (size_t)(((t-1)&1)*2 + d)*(B_*H_/2);
      // issue all 64 agent loads (pipelined), then MFMA
      u32x4 h0[8], h1[8];
      #pragma unroll
      for (int kc=0;kc<8;++kc){
        size_t b0 = (size_t)lc*128      + kc*16 + lh*4;
        size_t b1 = (size_t)(16+lc)*128 + kc*16 + lh*4;
        #pragma unroll
        for (int j=0;j<4;++j){
          h0[kc][j] = __hip_atomic_load(hb + b0 + j, __ATOMIC_RELAXED, __HIP_MEMORY_SCOPE_AGENT);
          h1[kc][j] = __hip_atomic_load(hb + b1 + j, __ATOMIC_RELAXED, __HIP_MEMORY_SCOPE_AGENT);
        }
      }
      #pragma unroll
      for (int kc=0;kc<8;++kc){
        bf16x8 a0 = __builtin_bit_cast(bf16x8, h0[kc]);
        bf16x8 a1 = __builtin_bit_cast(bf16x8, h1[kc]);
        #pragma unroll
        for (int nt=0;nt<4;++nt){
          acc[0][nt] = __builtin_amdgcn_mfma_f32_16x16x32_bf16(a0, wf[nt][kc], acc[0][nt], 0,0,0);
          acc[1][nt] = __builtin_amdgcn_mfma_f32_16x16x32_bf16(a1, wf[nt][kc], acc[1][nt], 0,0,0);
        }
      }
    }

    const int ts = d ? (255 - t) : t;
    uint32_t* hb_out = hbuf + (size_t)((t&1)*2 + d)*(B_*H_/2);
    #pragma unroll
    for (int mt=0;mt<2;++mt){
      #pragma unroll
      for (int r=0;r<4;++r){
        int fi = mt*16 + r;
        float zi = acc[mt][0][r] + b2f((ushort_t)xzv[(fi+0 )>>3][(fi+0 )&7]);
        float zf = acc[mt][1][r] + b2f((ushort_t)xzv[(fi+4 )>>3][(fi+4 )&7]);
        float zg = acc[mt][2][r] + b2f((ushort_t)xzv[(fi+8 )>>3][(fi+8 )&7]);
        float zo = acc[mt][3][r] + b2f((ushort_t)xzv[(fi+12)>>3][(fi+12)&7]);
        float ig = sig_f(zi), fg = sig_f(zf), gg = tanh_f(zg), og = sig_f(zo);
        float c = fg * cst[mt][r] + ig * gg;
        cst[mt][r] = c;
        float h = og * tanh_f(c);
        ushort_t h16 = f2b(h);
        int b = mt*16 + lh*4 + r;
        // cross-block handoff: pack (jj even, jj+1) into u32 via lane shuffle
        uint32_t mine = (uint32_t)h16;
        uint32_t partner = (uint32_t)__shfl_xor((int)mine, 1);
        if ((lc & 1) == 0){
          uint32_t packed = mine | (partner << 16);
          __hip_atomic_store(hb_out + (size_t)b*128 + (jj>>1), packed,
                             __ATOMIC_RELAXED, __HIP_MEMORY_SCOPE_AGENT);
        }
        hist[((size_t)(b*256 + ts))*512 + d*256 + jj] = h16;   // plain cached store
      }
    }
    asm volatile("s_waitcnt vmcnt(0)" ::: "memory");
    if (l == 0)
      __hip_atomic_fetch_add(flags + d*T_ + t, 1u, __ATOMIC_RELAXED, __HIP_MEMORY_SCOPE_AGENT);
  }
}

// =====================================================================
// C1: sq[m][x] = h[m]·W1[x][0:512], sk[m][x] = h[m]·W1[x][512:1024]
// =====================================================================
__global__ __launch_bounds__(256) void c1_k(char* __restrict__ ws, const ushort_t* __restrict__ W1,
                                            const ushort_t* __restrict__ hist)
{
  float* sq = (float*)(ws + OFF_SQ);
  float* sk = (float*)(ws + OFF_SK);
  const int dtf = *(const int*)(ws + OFF_DTYPE);
  int tid = threadIdx.x; int wv = tid>>6, l = tid&63;
  int row = blockIdx.x*4 + wv;
  bf16x8 hv = *(const bf16x8*)(hist + (size_t)row*512 + l*8);
  float hf[8];
  #pragma unroll
  for (int i=0;i<8;++i) hf[i] = b2f((ushort_t)hv[i]);
  #pragma unroll
  for (int x=0;x<10;++x){
    bf16x8 qv = load8(W1, (size_t)x*1024 + l*8, dtf);
    bf16x8 kv = load8(W1, (size_t)x*1024 + 512 + l*8, dtf);
    float pq=0.f, pk=0.f;
    #pragma unroll
    for (int i=0;i<8;++i){ pq += hf[i]*b2f((ushort_t)qv[i]); pk += hf[i]*b2f((ushort_t)kv[i]); }
    #pragma unroll
    for (int off=32; off>0; off>>=1){ pq += __shfl_xor(pq, off, 64); pk += __shfl_xor(pk, off, 64); }
    if (l == 0){ sq[row*10 + x] = pq; sk[row*10 + x] = pk; }
  }
}

// =====================================================================
// C2: a = sum_x tanh(sq+sk)*W2[x]; masked softmax -> bf16 watt
// =====================================================================
__global__ __launch_bounds__(256) void c2_k(char* __restrict__ ws, const ushort_t* __restrict__ W2,
                                            const ushort_t* __restrict__ mask)
{
  const float* sq = (const float*)(ws + OFF_SQ);
  const float* sk = (const float*)(ws + OFF_SK);
  ushort_t* watt = (ushort_t*)(ws + OFF_WATT);
  const int dtf = *(const int*)(ws + OFF_DTYPE);
  int tid = threadIdx.x; int wv = tid>>6, l = tid&63;
  int bq = blockIdx.x*4 + wv;
  int b  = bq >> 8;
  float sqv[10], w2v[10];
  #pragma unroll
  for (int x=0;x<10;++x){ sqv[x] = sq[(size_t)bq*10+x]; w2v[x] = loadS(W2, x, dtf); }
  float a[4];
  #pragma unroll
  for (int kk=0;kk<4;++kk){
    int k = kk*64 + l;
    const float* skp = sk + ((size_t)b*256 + k)*10;
    float s = 0.f;
    #pragma unroll
    for (int x=0;x<10;++x) s += tanh_f(sqv[x] + skp[x]) * w2v[x];
    float mval = loadS(mask, (size_t)b*256 + k, dtf);
    a[kk] = (mval == 0.f) ? -1e30f : s;
  }
  float mx = fmaxf(fmaxf(a[0],a[1]), fmaxf(a[2],a[3]));
  #pragma unroll
  for (int off=32; off>0; off>>=1) mx = fmaxf(mx, __shfl_xor(mx, off, 64));
  float e[4], ssum=0.f;
  #pragma unroll
  for (int kk=0;kk<4;++kk){ e[kk] = __expf(a[kk]-mx); ssum += e[kk]; }
  #pragma unroll
  for (int off=32; off>0; off>>=1) ssum += __shfl_xor(ssum, off, 64);
  float inv = 1.f/ssum;
  #pragma unroll
  for (int kk=0;kk<4;++kk) watt[(size_t)bq*256 + kk*64 + l] = f2b(e[kk]*inv);
}

// =====================================================================
extern "C" void kernel_launch(void* const* d_in, const int* in_sizes, int n_in,
                              void* d_out, int out_size, void* d_ws, size_t ws_size,
                              hipStream_t stream)
{
  const ushort_t* x     = (const ushort_t*)d_in[0];
  const ushort_t* mask  = (const ushort_t*)d_in[1];
  const ushort_t* Wih_f = (const ushort_t*)d_in[2];
  const ushort_t* Whh_f = (const ushort_t*)d_in[3];
  const ushort_t* b_f   = (const ushort_t*)d_in[4];
  const ushort_t* Wih_b = (const ushort_t*)d_in[5];
  const ushort_t* Whh_b = (const ushort_t*)d_in[6];
  const ushort_t* b_b   = (const ushort_t*)d_in[7];
  const ushort_t* W1    = (const ushort_t*)d_in[8];
  const ushort_t* W2    = (const ushort_t*)d_in[9];
  const ushort_t* W3    = (const ushort_t*)d_in[10];
  const ushort_t* b3    = (const ushort_t*)d_in[11];
  ushort_t* out = (ushort_t*)d_out;
  char* ws = (char*)d_ws;

  const bool conc = ws_size >= (size_t)NEED_CONC;
  ushort_t* hist = (ushort_t*)(ws + OFF_XZ + (conc ? 33554432u : 16777216u));

  hipMemsetAsync(ws, 0, 4096, stream);           // dtype flag + barrier flags
  detect_k<<<dim3(1), dim3(256), 0, stream>>>((const uint32_t*)d_in[0], ws);

  dim3 blk(256);
  if (conc){
    gemm_k<0><<<dim3(64,8,1), blk, 0, stream>>>(x, nullptr, Wih_f, b_f, nullptr, ws,
                                                DB_, DB_, DB_, 0, 1, 1, 0,0, 0L);
    gemm_k<0><<<dim3(64,8,1), blk, 0, stream>>>(x, nullptr, Wih_b, b_b, nullptr, ws,
                                                DB_, DB_, DB_, 1, 1, 1, 0,0, (long)XZ_DIR_ELEMS);
    rec_k<<<dim3(8), blk, 0, stream>>>(Whh_f, Whh_b, ws, hist, 0, (long)XZ_DIR_ELEMS);
  } else {
    gemm_k<0><<<dim3(64,8,1), blk, 0, stream>>>(x, nullptr, Wih_f, b_f, nullptr, ws,
                                                DB_, DB_, DB_, 0, 1, 1, 0,0, 0L);
    rec_k<<<dim3(4), blk, 0, stream>>>(Whh_f, Whh_b, ws, hist, 0, 0L);
    gemm_k<0><<<dim3(64,8,1), blk, 0, stream>>>(x, nullptr, Wih_b, b_b, nullptr, ws,
                                                DB_, DB_, DB_, 1, 1, 1, 0,0, 0L);
    rec_k<<<dim3(4), blk, 0, stream>>>(Whh_f, Whh_b, ws, hist, 1, 0L);
  }
  // attention
  c1_k<<<dim3(2048), blk, 0, stream>>>(ws, W1, hist);
  c2_k<<<dim3(2048), blk, 0, stream>>>(ws, W2, mask);
  // context = watt @ h (per batch), B row-major from hist
  gemm_k<3><<<dim3(2,4,32), blk, 0, stream>>>((ushort_t*)(ws+OFF_WATT), nullptr,
                                              hist, nullptr,
                                              (ushort_t*)(ws+OFF_CTX), ws,
                                              256, 512, 256, 0, 0, 0,
                                              65536L, 131072L, 131072L);
  // y = concat(h, ctx) @ W3^T + b3 -> d_out (dtype-matched store)
  gemm_k<2><<<dim3(64,4,1), blk, 0, stream>>>(hist, (ushort_t*)(ws+OFF_CTX),
                                              W3, b3, out, ws,
                                              512, 1024, 1024, 0, 0, 1, 0,0, 0L);
}

// Round 7
// 2064.060 us; speedup vs baseline: 1.7917x; 1.5506x over previous
//
#include <hip/hip_runtime.h>
#include <stdint.h>

// ---------------- problem constants ----------------
#define B_   32
#define T_   256
#define H_   256      // per-direction hidden
#define DB_  768      // input dim
#define DL_  512      // 2*H

// ---------------- workspace layout (bytes) ----------------
#define OFF_DTYPE 0u                          // int: 1 = inputs bf16, 0 = f32
#define OFF_FLAGS 256u                        // [2 dir][256 t] u32 flag counters (target 4)
#define OFF_HBUF  4096u                       // [2 parity][2 dir][32 b][128 u32] = 64 KB
#define OFF_XZ    69632u                      // swizzled xz, per-dir stride 8M elems (16 MB)
#define XZ_DIR_ELEMS 8388608u
#define NEED_CONC (OFF_XZ + 2u*16777216u + 8388608u)
// ---- aliased into the xz region (xz dead after rec) ----
#define OFF_CTX   OFF_XZ                      // context [32][256][512] bf16 = 8 MB
#define OFF_WATT  (OFF_XZ + 8388608u)         // attn weights [32][256][256] bf16 = 4 MB
#define OFF_SQ    (OFF_XZ + 12582912u)        // [8192][10] f32
#define OFF_SK    (OFF_SQ + 327680u)          // [8192][10] f32

typedef __attribute__((ext_vector_type(8))) short bf16x8;
typedef __attribute__((ext_vector_type(4))) float f32x4;
typedef __attribute__((ext_vector_type(4))) uint32_t u32x4;
typedef __attribute__((ext_vector_type(2))) uint64_t u64x2;
typedef unsigned short ushort_t;

__device__ __forceinline__ float b2f(ushort_t u){ union{float f; uint32_t i;} v; v.i=((uint32_t)u)<<16; return v.f; }
__device__ __forceinline__ ushort_t f2b(float f){
  union{float ff; uint32_t i;} v; v.ff=f;
  uint32_t r = v.i + 0x7fffu + ((v.i>>16)&1u);
  return (ushort_t)(r>>16);
}
__device__ __forceinline__ float sig_f(float x){ return 1.f/(1.f+__expf(-x)); }
__device__ __forceinline__ float tanh_f(float x){ return 1.f - 2.f/(1.f+__expf(2.f*x)); }

__device__ __forceinline__ bf16x8 load8(const ushort_t* p, size_t idx, int isbf){
  if (isbf) return *(const bf16x8*)(p + idx);
  const float* f = (const float*)p;
  bf16x8 r;
  #pragma unroll
  for (int i=0;i<8;++i) r[i] = (short)f2b(f[idx+i]);
  return r;
}
__device__ __forceinline__ float loadS(const ushort_t* p, size_t idx, int isbf){
  return isbf ? b2f(p[idx]) : ((const float*)p)[idx];
}

// volatile weight load: compiler cannot re-execute -> value stays VGPR-resident
__device__ __forceinline__ bf16x8 wload8(const ushort_t* p, size_t idx, int isbf){
  if (isbf){
    u32x4 raw = *(const volatile u32x4*)(p + idx);
    return __builtin_bit_cast(bf16x8, raw);
  } else {
    const float* fp = (const float*)p;
    f32x4 a = *(const volatile f32x4*)(fp + idx);
    f32x4 b = *(const volatile f32x4*)(fp + idx + 4);
    bf16x8 r;
    #pragma unroll
    for (int i=0;i<4;++i){ r[i] = (short)f2b(a[i]); r[4+i] = (short)f2b(b[i]); }
    return r;
  }
}

// =====================================================================
// dtype probe (R3-verified): votes f32 vs bf16 from exponent stats.
// =====================================================================
__global__ void detect_k(const uint32_t* __restrict__ x, char* __restrict__ ws){
  __shared__ int cnt;
  if (threadIdx.x == 0) cnt = 0;
  __syncthreads();
  int local = 0;
  #pragma unroll
  for (int i=0;i<4;++i){
    uint32_t w = x[threadIdx.x*4 + i];
    uint32_t lo = w & 0xFFFFu;
    int e = (int)((lo >> 7) & 0xFFu);
    if (e >= 118 && e <= 130) local++;
  }
  atomicAdd(&cnt, local);
  __syncthreads();
  if (threadIdx.x == 0) *(int*)(ws + OFF_DTYPE) = (cnt > 512) ? 1 : 0;
}

// =====================================================================
// Generic 128x128-tile bf16 MFMA GEMM (unchanged, R4/R5-verified).
// =====================================================================
template<int MODE>
__global__ __launch_bounds__(256,2) void gemm_k(
    const ushort_t* __restrict__ A0, const ushort_t* __restrict__ A2,
    const ushort_t* __restrict__ Bm, const ushort_t* __restrict__ bias,
    ushort_t* __restrict__ Cout, char* __restrict__ ws,
    int lda, int ldb, int K, int dir, int aIn, int bIn,
    long aOffZ, long bOffZ, long cOffZ)
{
  __shared__ ushort_t As[8192];
  __shared__ ushort_t Bs[8192];
  const int dtf = *(const int*)(ws + OFF_DTYPE);
  const int aBF = aIn ? dtf : 1;
  const int bBF = bIn ? dtf : 1;
  const int tid = threadIdx.x;
  const int l  = tid & 63, wv = tid >> 6;
  const int lc = l & 15,  lh = l >> 4;
  const int m0 = blockIdx.x * 128, n0 = blockIdx.y * 128;
  const int z  = blockIdx.z;
  const ushort_t* Abase = A0 + (size_t)z * aOffZ;
  const ushort_t* Bbase = Bm + (size_t)z * bOffZ;
  const int srow = tid >> 3;
  const int sch  = tid & 7;

  f32x4 acc[4][4];
  #pragma unroll
  for (int i=0;i<4;++i)
    #pragma unroll
    for (int j=0;j<4;++j) acc[i][j] = (f32x4){0.f,0.f,0.f,0.f};

  bf16x8 ra[4], rb[4];
  #pragma unroll
  for (int p=0;p<4;++p){
    int row = p*32 + srow;
    int kk  = (sch ^ (row & 7)) * 8;
    ra[p] = load8(Abase, (size_t)(m0+row)*lda + kk, aBF);
    if (MODE==3){
      int q = p*256 + tid, kr = q>>4, c = q&15;
      rb[p] = load8(Bbase, (size_t)kr*ldb + n0 + c*8, 1);
    } else {
      rb[p] = load8(Bbase, (size_t)(n0+row)*ldb + kk, bBF);
    }
  }

  const int mo = (wv&1)*64, no = (wv>>1)*64;

  for (int k0 = 0; k0 < K; k0 += 64) {
    #pragma unroll
    for (int p=0;p<4;++p){
      int row = p*32 + srow;
      *(bf16x8*)(&As[row*64 + sch*8]) = ra[p];
      if (MODE==3){
        int q = p*256 + tid, kr = q>>4, c = q&15;
        *(bf16x8*)(&Bs[kr*128 + c*8]) = rb[p];
      } else {
        *(bf16x8*)(&Bs[row*64 + sch*8]) = rb[p];
      }
    }
    __syncthreads();
    int k1 = k0 + 64;
    if (k1 < K) {
      #pragma unroll
      for (int p=0;p<4;++p){
        int row = p*32 + srow;
        int kk  = k1 + (sch ^ (row & 7)) * 8;
        if (MODE==2 && k1 >= 512)
          ra[p] = load8(A2, (size_t)(m0+row)*512 + (kk - 512), 1);
        else
          ra[p] = load8(Abase, (size_t)(m0+row)*lda + kk, aBF);
        if (MODE==3){
          int q = p*256 + tid, kr = q>>4, c = q&15;
          rb[p] = load8(Bbase, (size_t)(k1+kr)*ldb + n0 + c*8, 1);
        } else {
          rb[p] = load8(Bbase, (size_t)(n0+row)*ldb + kk, bBF);
        }
      }
    }
    #pragma unroll
    for (int kc=0;kc<2;++kc){
      bf16x8 af[4], bfv[4];
      #pragma unroll
      for (int it=0;it<4;++it){
        int m = mo + it*16 + lc;
        int gc = kc*4 + lh;
        af[it]  = *(const bf16x8*)(&As[m*64 + ((gc ^ (m&7))*8)]);
        int n = no + it*16 + lc;
        if (MODE==3){
          #pragma unroll
          for (int j=0;j<8;++j) bfv[it][j] = (short)Bs[(kc*32 + lh*8 + j)*128 + n];
        } else {
          bfv[it] = *(const bf16x8*)(&Bs[n*64 + ((gc ^ (n&7))*8)]);
        }
      }
      #pragma unroll
      for (int mt=0;mt<4;++mt)
        #pragma unroll
        for (int nt=0;nt<4;++nt)
          acc[mt][nt] = __builtin_amdgcn_mfma_f32_16x16x32_bf16(af[mt], bfv[nt], acc[mt][nt], 0,0,0);
    }
    __syncthreads();
  }

  ushort_t* xzsw = (ushort_t*)(ws + OFF_XZ);
  #pragma unroll
  for (int mt=0;mt<4;++mt){
    #pragma unroll
    for (int nt=0;nt<4;++nt){
      #pragma unroll
      for (int r=0;r<4;++r){
        int m = m0 + mo + mt*16 + lh*4 + r;
        int n = n0 + no + nt*16 + lc;
        float v = acc[mt][nt][r];
        if (MODE==0){
          v += loadS(bias, n, bBF);
          int b = m >> 8, t = m & 255;
          int ts = dir ? (255 - t) : t;
          int q = n >> 8, jm = n & 255;
          int w = jm >> 6, jj = jm & 63, wvv = jj >> 4, colj = jj & 15;
          int lane = ((b >> 2) & 3)*16 + colj;
          int idx  = (b >> 4)*16 + q*4 + (b & 3);
          size_t e = (((size_t)(w*4 + wvv)*256 + ts)*2048) + (size_t)lane*32 + idx;
          xzsw[e + (size_t)cOffZ] = f2b(v);
        } else if (MODE==3){
          Cout[(size_t)z*cOffZ + (size_t)m*DL_ + n] = f2b(v);
        } else {
          v += loadS(bias, n, bBF);
          if (dtf) Cout[(size_t)m*DL_ + n] = f2b(v);
          else     ((float*)Cout)[(size_t)m*DL_ + n] = v;
        }
      }
    }
  }
}

// =====================================================================
// Persistent BiLSTM recurrence.
// - Whh fragments loaded VOLATILE -> forced VGPR-resident (no per-step
//   re-stream of 512 KB/dir, the R4/R5 hidden cost).
// - Handoff: relaxed agent u32 stores -> waitcnt -> barrier -> 1 flag
//   RMW per block (target 4/dir); reader: tid0 relaxed poll -> barrier ->
//   32 relaxed agent u64 loads (pipelined, stale-cache-proof).
// =====================================================================
__global__ __launch_bounds__(256,1) void rec_k(
    const ushort_t* __restrict__ Whh_f, const ushort_t* __restrict__ Whh_b,
    char* __restrict__ ws, ushort_t* __restrict__ hist,
    int dParam, long xzDirStride)
{
  const int d = (gridDim.x == 8) ? (int)(blockIdx.x >> 2) : dParam;
  const int w = blockIdx.x & 3;
  const int tid = threadIdx.x;
  const int wv = tid >> 6, l = tid & 63;
  const int lc = l & 15, lh = l >> 4;
  const int dtf = *(const int*)(ws + OFF_DTYPE);

  uint32_t* flags = (uint32_t*)(ws + OFF_FLAGS);
  uint32_t* hbuf  = (uint32_t*)(ws + OFF_HBUF);     // u32-packed bf16 pairs
  const ushort_t* xz = (const ushort_t*)(ws + OFF_XZ) + (size_t)d * xzDirStride;
  const ushort_t* Whh = d ? Whh_b : Whh_f;

  const int jj = 64*w + 16*wv + lc;

  bf16x8 wf[4][8];                    // [gate][k-chunk], FORCED persistent
  #pragma unroll
  for (int nt=0;nt<4;++nt)
    #pragma unroll
    for (int kc=0;kc<8;++kc)
      wf[nt][kc] = wload8(Whh, (size_t)(nt*256 + jj)*256 + kc*32 + lh*8, dtf);

  float cst[2][4];
  #pragma unroll
  for (int i=0;i<2;++i){ cst[i][0]=0.f; cst[i][1]=0.f; cst[i][2]=0.f; cst[i][3]=0.f; }

  const ushort_t* xzb = xz + ((size_t)(w*4+wv)*256)*2048 + (size_t)l*32;

  for (int t=0; t<T_; ++t){
    bf16x8 xzv[4];
    #pragma unroll
    for (int i=0;i<4;++i) xzv[i] = *(const bf16x8*)(xzb + (size_t)t*2048 + i*8);

    f32x4 acc[2][4];
    #pragma unroll
    for (int i=0;i<2;++i)
      #pragma unroll
      for (int j=0;j<4;++j) acc[i][j] = (f32x4){0.f,0.f,0.f,0.f};

    if (t > 0){
      if (tid == 0){
        const uint32_t* fl = flags + d*T_ + (t-1);
        while (__hip_atomic_load(fl, __ATOMIC_RELAXED, __HIP_MEMORY_SCOPE_AGENT) < 4u)
          __builtin_amdgcn_s_sleep(1);
      }
      __syncthreads();

      const uint64_t* hb64 = (const uint64_t*)(hbuf + (size_t)(((t-1)&1)*2 + d)*(B_*H_/2));
      uint64_t h0[8][2], h1[8][2];
      #pragma unroll
      for (int kc=0;kc<8;++kc){
        size_t b0 = ((size_t)lc*128      + kc*16 + lh*4) >> 1;
        size_t b1 = ((size_t)(16+lc)*128 + kc*16 + lh*4) >> 1;
        h0[kc][0] = __hip_atomic_load(hb64 + b0,     __ATOMIC_RELAXED, __HIP_MEMORY_SCOPE_AGENT);
        h0[kc][1] = __hip_atomic_load(hb64 + b0 + 1, __ATOMIC_RELAXED, __HIP_MEMORY_SCOPE_AGENT);
        h1[kc][0] = __hip_atomic_load(hb64 + b1,     __ATOMIC_RELAXED, __HIP_MEMORY_SCOPE_AGENT);
        h1[kc][1] = __hip_atomic_load(hb64 + b1 + 1, __ATOMIC_RELAXED, __HIP_MEMORY_SCOPE_AGENT);
      }
      #pragma unroll
      for (int kc=0;kc<8;++kc){
        u64x2 p0; p0[0] = h0[kc][0]; p0[1] = h0[kc][1];
        u64x2 p1; p1[0] = h1[kc][0]; p1[1] = h1[kc][1];
        bf16x8 a0 = __builtin_bit_cast(bf16x8, p0);
        bf16x8 a1 = __builtin_bit_cast(bf16x8, p1);
        #pragma unroll
        for (int nt=0;nt<4;++nt){
          acc[0][nt] = __builtin_amdgcn_mfma_f32_16x16x32_bf16(a0, wf[nt][kc], acc[0][nt], 0,0,0);
          acc[1][nt] = __builtin_amdgcn_mfma_f32_16x16x32_bf16(a1, wf[nt][kc], acc[1][nt], 0,0,0);
        }
      }
    }

    const int ts = d ? (255 - t) : t;
    uint32_t* hb_out = hbuf + (size_t)((t&1)*2 + d)*(B_*H_/2);
    #pragma unroll
    for (int mt=0;mt<2;++mt){
      #pragma unroll
      for (int r=0;r<4;++r){
        int fi = mt*16 + r;
        float zi = acc[mt][0][r] + b2f((ushort_t)xzv[(fi+0 )>>3][(fi+0 )&7]);
        float zf = acc[mt][1][r] + b2f((ushort_t)xzv[(fi+4 )>>3][(fi+4 )&7]);
        float zg = acc[mt][2][r] + b2f((ushort_t)xzv[(fi+8 )>>3][(fi+8 )&7]);
        float zo = acc[mt][3][r] + b2f((ushort_t)xzv[(fi+12)>>3][(fi+12)&7]);
        float ig = sig_f(zi), fg = sig_f(zf), gg = tanh_f(zg), og = sig_f(zo);
        float c = fg * cst[mt][r] + ig * gg;
        cst[mt][r] = c;
        float h = og * tanh_f(c);
        ushort_t h16 = f2b(h);
        int b = mt*16 + lh*4 + r;
        uint32_t mine = (uint32_t)h16;
        uint32_t partner = (uint32_t)__shfl_xor((int)mine, 1);
        if ((lc & 1) == 0){
          uint32_t packed = mine | (partner << 16);
          __hip_atomic_store(hb_out + (size_t)b*128 + (jj>>1), packed,
                             __ATOMIC_RELAXED, __HIP_MEMORY_SCOPE_AGENT);
        }
        hist[((size_t)(b*256 + ts))*512 + d*256 + jj] = h16;   // plain cached store
      }
    }
    __builtin_amdgcn_s_waitcnt(0);   // drain stores before barrier/flag
    __syncthreads();
    if (tid == 0)
      __hip_atomic_fetch_add(flags + d*T_ + t, 1u, __ATOMIC_RELAXED, __HIP_MEMORY_SCOPE_AGENT);
  }
}

// =====================================================================
// C1: sq[m][x] = h[m]·W1[x][0:512], sk[m][x] = h[m]·W1[x][512:1024]
// =====================================================================
__global__ __launch_bounds__(256) void c1_k(char* __restrict__ ws, const ushort_t* __restrict__ W1,
                                            const ushort_t* __restrict__ hist)
{
  float* sq = (float*)(ws + OFF_SQ);
  float* sk = (float*)(ws + OFF_SK);
  const int dtf = *(const int*)(ws + OFF_DTYPE);
  int tid = threadIdx.x; int wv = tid>>6, l = tid&63;
  int row = blockIdx.x*4 + wv;
  bf16x8 hv = *(const bf16x8*)(hist + (size_t)row*512 + l*8);
  float hf[8];
  #pragma unroll
  for (int i=0;i<8;++i) hf[i] = b2f((ushort_t)hv[i]);
  #pragma unroll
  for (int x=0;x<10;++x){
    bf16x8 qv = load8(W1, (size_t)x*1024 + l*8, dtf);
    bf16x8 kv = load8(W1, (size_t)x*1024 + 512 + l*8, dtf);
    float pq=0.f, pk=0.f;
    #pragma unroll
    for (int i=0;i<8;++i){ pq += hf[i]*b2f((ushort_t)qv[i]); pk += hf[i]*b2f((ushort_t)kv[i]); }
    #pragma unroll
    for (int off=32; off>0; off>>=1){ pq += __shfl_xor(pq, off, 64); pk += __shfl_xor(pk, off, 64); }
    if (l == 0){ sq[row*10 + x] = pq; sk[row*10 + x] = pk; }
  }
}

// =====================================================================
// C2: a = sum_x tanh(sq+sk)*W2[x]; masked softmax -> bf16 watt
// =====================================================================
__global__ __launch_bounds__(256) void c2_k(char* __restrict__ ws, const ushort_t* __restrict__ W2,
                                            const ushort_t* __restrict__ mask)
{
  const float* sq = (const float*)(ws + OFF_SQ);
  const float* sk = (const float*)(ws + OFF_SK);
  ushort_t* watt = (ushort_t*)(ws + OFF_WATT);
  const int dtf = *(const int*)(ws + OFF_DTYPE);
  int tid = threadIdx.x; int wv = tid>>6, l = tid&63;
  int bq = blockIdx.x*4 + wv;
  int b  = bq >> 8;
  float sqv[10], w2v[10];
  #pragma unroll
  for (int x=0;x<10;++x){ sqv[x] = sq[(size_t)bq*10+x]; w2v[x] = loadS(W2, x, dtf); }
  float a[4];
  #pragma unroll
  for (int kk=0;kk<4;++kk){
    int k = kk*64 + l;
    const float* skp = sk + ((size_t)b*256 + k)*10;
    float s = 0.f;
    #pragma unroll
    for (int x=0;x<10;++x) s += tanh_f(sqv[x] + skp[x]) * w2v[x];
    float mval = loadS(mask, (size_t)b*256 + k, dtf);
    a[kk] = (mval == 0.f) ? -1e30f : s;
  }
  float mx = fmaxf(fmaxf(a[0],a[1]), fmaxf(a[2],a[3]));
  #pragma unroll
  for (int off=32; off>0; off>>=1) mx = fmaxf(mx, __shfl_xor(mx, off, 64));
  float e[4], ssum=0.f;
  #pragma unroll
  for (int kk=0;kk<4;++kk){ e[kk] = __expf(a[kk]-mx); ssum += e[kk]; }
  #pragma unroll
  for (int off=32; off>0; off>>=1) ssum += __shfl_xor(ssum, off, 64);
  float inv = 1.f/ssum;
  #pragma unroll
  for (int kk=0;kk<4;++kk) watt[(size_t)bq*256 + kk*64 + l] = f2b(e[kk]*inv);
}

// =====================================================================
extern "C" void kernel_launch(void* const* d_in, const int* in_sizes, int n_in,
                              void* d_out, int out_size, void* d_ws, size_t ws_size,
                              hipStream_t stream)
{
  const ushort_t* x     = (const ushort_t*)d_in[0];
  const ushort_t* mask  = (const ushort_t*)d_in[1];
  const ushort_t* Wih_f = (const ushort_t*)d_in[2];
  const ushort_t* Whh_f = (const ushort_t*)d_in[3];
  const ushort_t* b_f   = (const ushort_t*)d_in[4];
  const ushort_t* Wih_b = (const ushort_t*)d_in[5];
  const ushort_t* Whh_b = (const ushort_t*)d_in[6];
  const ushort_t* b_b   = (const ushort_t*)d_in[7];
  const ushort_t* W1    = (const ushort_t*)d_in[8];
  const ushort_t* W2    = (const ushort_t*)d_in[9];
  const ushort_t* W3    = (const ushort_t*)d_in[10];
  const ushort_t* b3    = (const ushort_t*)d_in[11];
  ushort_t* out = (ushort_t*)d_out;
  char* ws = (char*)d_ws;

  const bool conc = ws_size >= (size_t)NEED_CONC;
  ushort_t* hist = (ushort_t*)(ws + OFF_XZ + (conc ? 33554432u : 16777216u));

  hipMemsetAsync(ws, 0, 4096, stream);           // dtype flag + barrier flags
  detect_k<<<dim3(1), dim3(256), 0, stream>>>((const uint32_t*)d_in[0], ws);

  dim3 blk(256);
  if (conc){
    gemm_k<0><<<dim3(64,8,1), blk, 0, stream>>>(x, nullptr, Wih_f, b_f, nullptr, ws,
                                                DB_, DB_, DB_, 0, 1, 1, 0,0, 0L);
    gemm_k<0><<<dim3(64,8,1), blk, 0, stream>>>(x, nullptr, Wih_b, b_b, nullptr, ws,
                                                DB_, DB_, DB_, 1, 1, 1, 0,0, (long)XZ_DIR_ELEMS);
    rec_k<<<dim3(8), blk, 0, stream>>>(Whh_f, Whh_b, ws, hist, 0, (long)XZ_DIR_ELEMS);
  } else {
    gemm_k<0><<<dim3(64,8,1), blk, 0, stream>>>(x, nullptr, Wih_f, b_f, nullptr, ws,
                                                DB_, DB_, DB_, 0, 1, 1, 0,0, 0L);
    rec_k<<<dim3(4), blk, 0, stream>>>(Whh_f, Whh_b, ws, hist, 0, 0L);
    gemm_k<0><<<dim3(64,8,1), blk, 0, stream>>>(x, nullptr, Wih_b, b_b, nullptr, ws,
                                                DB_, DB_, DB_, 1, 1, 1, 0,0, 0L);
    rec_k<<<dim3(4), blk, 0, stream>>>(Whh_f, Whh_b, ws, hist, 1, 0L);
  }
  // attention
  c1_k<<<dim3(2048), blk, 0, stream>>>(ws, W1, hist);
  c2_k<<<dim3(2048), blk, 0, stream>>>(ws, W2, mask);
  // context = watt @ h (per batch), B row-major from hist
  gemm_k<3><<<dim3(2,4,32), blk, 0, stream>>>((ushort_t*)(ws+OFF_WATT), nullptr,
                                              hist, nullptr,
                                              (ushort_t*)(ws+OFF_CTX), ws,
                                              256, 512, 256, 0, 0, 0,
                                              65536L, 131072L, 131072L);
  // y = concat(h, ctx) @ W3^T + b3 -> d_out (dtype-matched store)
  gemm_k<2><<<dim3(64,4,1), blk, 0, stream>>>(hist, (ushort_t*)(ws+OFF_CTX),
                                              W3, b3, out, ws,
                                              512, 1024, 1024, 0, 0, 1, 0,0, 0L);
}

// Round 8
// 1440.122 us; speedup vs baseline: 2.5679x; 1.4333x over previous
//
#include <hip/hip_runtime.h>
#include <stdint.h>

// ---------------- problem constants ----------------
#define B_   32
#define T_   256
#define H_   256      // per-direction hidden
#define DB_  768      // input dim
#define DL_  512      // 2*H

// ---------------- workspace layout (bytes) ----------------
#define OFF_DTYPE 0u                          // int: 1 = inputs bf16, 0 = f32
#define OFF_FLAGS 256u                        // [2 dir][256 t] u32 flag counters (target 8)
#define OFF_HBUF  4096u                       // [2 parity][2 dir][32 b][128 u32] = 64 KB
#define OFF_XZ    69632u                      // swizzled xz, per-dir stride 8M elems (16 MB)
#define XZ_DIR_ELEMS 8388608u
#define NEED_CONC (OFF_XZ + 2u*16777216u + 8388608u)
// ---- aliased into the xz region (xz dead after rec) ----
#define OFF_CTX   OFF_XZ                      // context [32][256][512] bf16 = 8 MB
#define OFF_WATT  (OFF_XZ + 8388608u)         // attn weights [32][256][256] bf16 = 4 MB
#define OFF_SQ    (OFF_XZ + 12582912u)        // [8192][10] f32
#define OFF_SK    (OFF_SQ + 327680u)          // [8192][10] f32

typedef __attribute__((ext_vector_type(8))) short bf16x8;
typedef __attribute__((ext_vector_type(4))) float f32x4;
typedef __attribute__((ext_vector_type(4))) uint32_t u32x4;
typedef unsigned short ushort_t;

__device__ __forceinline__ float b2f(ushort_t u){ union{float f; uint32_t i;} v; v.i=((uint32_t)u)<<16; return v.f; }
__device__ __forceinline__ ushort_t f2b(float f){
  union{float ff; uint32_t i;} v; v.ff=f;
  uint32_t r = v.i + 0x7fffu + ((v.i>>16)&1u);
  return (ushort_t)(r>>16);
}
__device__ __forceinline__ float sig_f(float x){ return 1.f/(1.f+__expf(-x)); }
__device__ __forceinline__ float tanh_f(float x){ return 1.f - 2.f/(1.f+__expf(2.f*x)); }

__device__ __forceinline__ bf16x8 load8(const ushort_t* p, size_t idx, int isbf){
  if (isbf) return *(const bf16x8*)(p + idx);
  const float* f = (const float*)p;
  bf16x8 r;
  #pragma unroll
  for (int i=0;i<8;++i) r[i] = (short)f2b(f[idx+i]);
  return r;
}
__device__ __forceinline__ float loadS(const ushort_t* p, size_t idx, int isbf){
  return isbf ? b2f(p[idx]) : ((const float*)p)[idx];
}

// =====================================================================
// dtype probe (R3-verified): votes f32 vs bf16 from exponent stats.
// =====================================================================
__global__ void detect_k(const uint32_t* __restrict__ x, char* __restrict__ ws){
  __shared__ int cnt;
  if (threadIdx.x == 0) cnt = 0;
  __syncthreads();
  int local = 0;
  #pragma unroll
  for (int i=0;i<4;++i){
    uint32_t w = x[threadIdx.x*4 + i];
    uint32_t lo = w & 0xFFFFu;
    int e = (int)((lo >> 7) & 0xFFu);
    if (e >= 118 && e <= 130) local++;
  }
  atomicAdd(&cnt, local);
  __syncthreads();
  if (threadIdx.x == 0) *(int*)(ws + OFF_DTYPE) = (cnt > 512) ? 1 : 0;
}

// =====================================================================
// Generic 128x128-tile bf16 MFMA GEMM (unchanged, R4-R7-verified).
// =====================================================================
template<int MODE>
__global__ __launch_bounds__(256,2) void gemm_k(
    const ushort_t* __restrict__ A0, const ushort_t* __restrict__ A2,
    const ushort_t* __restrict__ Bm, const ushort_t* __restrict__ bias,
    ushort_t* __restrict__ Cout, char* __restrict__ ws,
    int lda, int ldb, int K, int dir, int aIn, int bIn,
    long aOffZ, long bOffZ, long cOffZ)
{
  __shared__ ushort_t As[8192];
  __shared__ ushort_t Bs[8192];
  const int dtf = *(const int*)(ws + OFF_DTYPE);
  const int aBF = aIn ? dtf : 1;
  const int bBF = bIn ? dtf : 1;
  const int tid = threadIdx.x;
  const int l  = tid & 63, wv = tid >> 6;
  const int lc = l & 15,  lh = l >> 4;
  const int m0 = blockIdx.x * 128, n0 = blockIdx.y * 128;
  const int z  = blockIdx.z;
  const ushort_t* Abase = A0 + (size_t)z * aOffZ;
  const ushort_t* Bbase = Bm + (size_t)z * bOffZ;
  const int srow = tid >> 3;
  const int sch  = tid & 7;

  f32x4 acc[4][4];
  #pragma unroll
  for (int i=0;i<4;++i)
    #pragma unroll
    for (int j=0;j<4;++j) acc[i][j] = (f32x4){0.f,0.f,0.f,0.f};

  bf16x8 ra[4], rb[4];
  #pragma unroll
  for (int p=0;p<4;++p){
    int row = p*32 + srow;
    int kk  = (sch ^ (row & 7)) * 8;
    ra[p] = load8(Abase, (size_t)(m0+row)*lda + kk, aBF);
    if (MODE==3){
      int q = p*256 + tid, kr = q>>4, c = q&15;
      rb[p] = load8(Bbase, (size_t)kr*ldb + n0 + c*8, 1);
    } else {
      rb[p] = load8(Bbase, (size_t)(n0+row)*ldb + kk, bBF);
    }
  }

  const int mo = (wv&1)*64, no = (wv>>1)*64;

  for (int k0 = 0; k0 < K; k0 += 64) {
    #pragma unroll
    for (int p=0;p<4;++p){
      int row = p*32 + srow;
      *(bf16x8*)(&As[row*64 + sch*8]) = ra[p];
      if (MODE==3){
        int q = p*256 + tid, kr = q>>4, c = q&15;
        *(bf16x8*)(&Bs[kr*128 + c*8]) = rb[p];
      } else {
        *(bf16x8*)(&Bs[row*64 + sch*8]) = rb[p];
      }
    }
    __syncthreads();
    int k1 = k0 + 64;
    if (k1 < K) {
      #pragma unroll
      for (int p=0;p<4;++p){
        int row = p*32 + srow;
        int kk  = k1 + (sch ^ (row & 7)) * 8;
        if (MODE==2 && k1 >= 512)
          ra[p] = load8(A2, (size_t)(m0+row)*512 + (kk - 512), 1);
        else
          ra[p] = load8(Abase, (size_t)(m0+row)*lda + kk, aBF);
        if (MODE==3){
          int q = p*256 + tid, kr = q>>4, c = q&15;
          rb[p] = load8(Bbase, (size_t)(k1+kr)*ldb + n0 + c*8, 1);
        } else {
          rb[p] = load8(Bbase, (size_t)(n0+row)*ldb + kk, bBF);
        }
      }
    }
    #pragma unroll
    for (int kc=0;kc<2;++kc){
      bf16x8 af[4], bfv[4];
      #pragma unroll
      for (int it=0;it<4;++it){
        int m = mo + it*16 + lc;
        int gc = kc*4 + lh;
        af[it]  = *(const bf16x8*)(&As[m*64 + ((gc ^ (m&7))*8)]);
        int n = no + it*16 + lc;
        if (MODE==3){
          #pragma unroll
          for (int j=0;j<8;++j) bfv[it][j] = (short)Bs[(kc*32 + lh*8 + j)*128 + n];
        } else {
          bfv[it] = *(const bf16x8*)(&Bs[n*64 + ((gc ^ (n&7))*8)]);
        }
      }
      #pragma unroll
      for (int mt=0;mt<4;++mt)
        #pragma unroll
        for (int nt=0;nt<4;++nt)
          acc[mt][nt] = __builtin_amdgcn_mfma_f32_16x16x32_bf16(af[mt], bfv[nt], acc[mt][nt], 0,0,0);
    }
    __syncthreads();
  }

  ushort_t* xzsw = (ushort_t*)(ws + OFF_XZ);
  #pragma unroll
  for (int mt=0;mt<4;++mt){
    #pragma unroll
    for (int nt=0;nt<4;++nt){
      #pragma unroll
      for (int r=0;r<4;++r){
        int m = m0 + mo + mt*16 + lh*4 + r;
        int n = n0 + no + nt*16 + lc;
        float v = acc[mt][nt][r];
        if (MODE==0){
          v += loadS(bias, n, bBF);
          int b = m >> 8, t = m & 255;
          int ts = dir ? (255 - t) : t;
          int q = n >> 8, jm = n & 255;
          int w = jm >> 6, jj = jm & 63, wvv = jj >> 4, colj = jj & 15;
          int lane = ((b >> 2) & 3)*16 + colj;
          int idx  = (b >> 4)*16 + q*4 + (b & 3);
          size_t e = (((size_t)(w*4 + wvv)*256 + ts)*2048) + (size_t)lane*32 + idx;
          xzsw[e + (size_t)cOffZ] = f2b(v);
        } else if (MODE==3){
          Cout[(size_t)z*cOffZ + (size_t)m*DL_ + n] = f2b(v);
        } else {
          v += loadS(bias, n, bBF);
          if (dtf) Cout[(size_t)m*DL_ + n] = f2b(v);
          else     ((float*)Cout)[(size_t)m*DL_ + n] = v;
        }
      }
    }
  }
}

// =====================================================================
// Persistent BiLSTM recurrence, v4.
// 8 blocks/dir, 32 hidden units/block; weights in 64 KB static LDS
// (deterministic residency — no VGPR spill, no per-step restream).
// Wave wv = (bh=wv&1 batch-half, hh=wv>>1 hidden-16-group).
// Per step: prefetch xz -> tid0 poll flag==8 -> barrier -> agent-acquire
// fence (inv clean L1/L2) -> 8 plain dwordx4 h-loads (pipelined LLC) ->
// ds_read weights + 32 MFMA -> cell -> relaxed agent h-stores (packed
// u32) + plain hist stores -> waitcnt -> barrier -> 1 flag RMW / block.
// =====================================================================
__global__ __launch_bounds__(256,1) void rec_k(
    const ushort_t* __restrict__ Whh_f, const ushort_t* __restrict__ Whh_b,
    char* __restrict__ ws, ushort_t* __restrict__ hist,
    int dParam, long xzDirStride)
{
  __shared__ ushort_t wlds[32768];   // 64 KB: 64 frags x 1 KB
  const int d  = (gridDim.x == 16) ? (int)(blockIdx.x >> 3) : dParam;
  const int bw = (int)(blockIdx.x & 7);
  const int tid = threadIdx.x;
  const int wv = tid >> 6, l = tid & 63;
  const int lc = l & 15, lh = l >> 4;
  const int bh = wv & 1, hh = wv >> 1;
  const int dtf = *(const int*)(ws + OFF_DTYPE);

  uint32_t* flags = (uint32_t*)(ws + OFF_FLAGS);
  uint32_t* hbuf  = (uint32_t*)(ws + OFF_HBUF);     // u32-packed bf16 pairs
  const ushort_t* xz = (const ushort_t*)(ws + OFF_XZ) + (size_t)d * xzDirStride;
  const ushort_t* Whh = d ? Whh_b : Whh_f;

  const int jj = bw*32 + hh*16 + lc;    // this lane's hidden unit
  const int g  = bw*2 + hh;             // hidden-16-group for xz layout

  // ---- stage this block's 64 KB weight slice into LDS ----
  // fragment f = (fhh*4 + fnt)*8 + fkc ; lane l holds elems for
  // col = bw*32 + fhh*16 + (l&15), k = fkc*32 + (l>>4)*8 .. +8
  #pragma unroll
  for (int i=0;i<16;++i){
    int f   = wv*16 + i;
    int fhh = f >> 5, fnt = (f >> 3) & 3, fkc = f & 7;
    int row = fnt*256 + bw*32 + fhh*16 + lc;
    bf16x8 v = load8(Whh, (size_t)row*256 + fkc*32 + lh*8, dtf);
    *(bf16x8*)(&wlds[f*512 + l*8]) = v;
  }
  __syncthreads();
  const int wbase = (hh*4)*8;   // this wave's fragment group base (nt=0,kc=0)

  float cst[4] = {0.f, 0.f, 0.f, 0.f};

  const ushort_t* xzb = xz + (size_t)g*256*2048 + (size_t)l*32 + bh*16;

  for (int t=0; t<T_; ++t){
    // prefetch xz[t] (plain loads; safe across acquire fence: xz is
    // written once before this kernel, any cached copy is valid)
    bf16x8 xzv[2];
    xzv[0] = *(const bf16x8*)(xzb + (size_t)t*2048);
    xzv[1] = *(const bf16x8*)(xzb + (size_t)t*2048 + 8);

    f32x4 acc[4];
    #pragma unroll
    for (int j=0;j<4;++j) acc[j] = (f32x4){0.f,0.f,0.f,0.f};

    if (t > 0){
      if (tid == 0){
        const uint32_t* fl = flags + d*T_ + (t-1);
        while (__hip_atomic_load(fl, __ATOMIC_RELAXED, __HIP_MEMORY_SCOPE_AGENT) < 8u)
          __builtin_amdgcn_s_sleep(1);
      }
      __syncthreads();
      __builtin_amdgcn_fence(__ATOMIC_ACQUIRE, "agent");   // inv clean L1/L2

      const uint32_t* hb = hbuf + (size_t)(((t-1)&1)*2 + d)*(B_*H_/2);
      u32x4 hreg[8];
      #pragma unroll
      for (int kc=0;kc<8;++kc)
        hreg[kc] = *(const u32x4*)(hb + (size_t)(bh*16+lc)*128 + kc*16 + lh*4);

      #pragma unroll
      for (int kc=0;kc<8;++kc){
        bf16x8 a = __builtin_bit_cast(bf16x8, hreg[kc]);
        #pragma unroll
        for (int nt=0;nt<4;++nt){
          bf16x8 wfrag = *(const bf16x8*)(&wlds[(wbase + nt*8 + kc)*512 + l*8]);
          acc[nt] = __builtin_amdgcn_mfma_f32_16x16x32_bf16(a, wfrag, acc[nt], 0,0,0);
        }
      }
    }

    const int ts = d ? (255 - t) : t;
    uint32_t* hb_out = hbuf + (size_t)((t&1)*2 + d)*(B_*H_/2);
    #pragma unroll
    for (int r=0;r<4;++r){
      float zi = acc[0][r] + b2f((ushort_t)xzv[(r+0 )>>3][(r+0 )&7]);
      float zf = acc[1][r] + b2f((ushort_t)xzv[(r+4 )>>3][(r+4 )&7]);
      float zg = acc[2][r] + b2f((ushort_t)xzv[(r+8 )>>3][(r+8 )&7]);
      float zo = acc[3][r] + b2f((ushort_t)xzv[(r+12)>>3][(r+12)&7]);
      float ig = sig_f(zi), fg = sig_f(zf), gg = tanh_f(zg), og = sig_f(zo);
      float c = fg * cst[r] + ig * gg;
      cst[r] = c;
      float h = og * tanh_f(c);
      ushort_t h16 = f2b(h);
      int b = bh*16 + lh*4 + r;
      uint32_t mine = (uint32_t)h16;
      uint32_t partner = (uint32_t)__shfl_xor((int)mine, 1);
      if ((lc & 1) == 0){
        uint32_t packed = mine | (partner << 16);
        __hip_atomic_store(hb_out + (size_t)b*128 + (jj>>1), packed,
                           __ATOMIC_RELAXED, __HIP_MEMORY_SCOPE_AGENT);
      }
      hist[((size_t)(b*256 + ts))*512 + d*256 + jj] = h16;   // plain cached store
    }
    __builtin_amdgcn_s_waitcnt(0);   // drain stores before flagging
    __syncthreads();
    if (tid == 0)
      __hip_atomic_fetch_add(flags + d*T_ + t, 1u, __ATOMIC_RELAXED, __HIP_MEMORY_SCOPE_AGENT);
  }
}

// =====================================================================
// C1: sq[m][x] = h[m]·W1[x][0:512], sk[m][x] = h[m]·W1[x][512:1024]
// =====================================================================
__global__ __launch_bounds__(256) void c1_k(char* __restrict__ ws, const ushort_t* __restrict__ W1,
                                            const ushort_t* __restrict__ hist)
{
  float* sq = (float*)(ws + OFF_SQ);
  float* sk = (float*)(ws + OFF_SK);
  const int dtf = *(const int*)(ws + OFF_DTYPE);
  int tid = threadIdx.x; int wv = tid>>6, l = tid&63;
  int row = blockIdx.x*4 + wv;
  bf16x8 hv = *(const bf16x8*)(hist + (size_t)row*512 + l*8);
  float hf[8];
  #pragma unroll
  for (int i=0;i<8;++i) hf[i] = b2f((ushort_t)hv[i]);
  #pragma unroll
  for (int x=0;x<10;++x){
    bf16x8 qv = load8(W1, (size_t)x*1024 + l*8, dtf);
    bf16x8 kv = load8(W1, (size_t)x*1024 + 512 + l*8, dtf);
    float pq=0.f, pk=0.f;
    #pragma unroll
    for (int i=0;i<8;++i){ pq += hf[i]*b2f((ushort_t)qv[i]); pk += hf[i]*b2f((ushort_t)kv[i]); }
    #pragma unroll
    for (int off=32; off>0; off>>=1){ pq += __shfl_xor(pq, off, 64); pk += __shfl_xor(pk, off, 64); }
    if (l == 0){ sq[row*10 + x] = pq; sk[row*10 + x] = pk; }
  }
}

// =====================================================================
// C2: a = sum_x tanh(sq+sk)*W2[x]; masked softmax -> bf16 watt
// =====================================================================
__global__ __launch_bounds__(256) void c2_k(char* __restrict__ ws, const ushort_t* __restrict__ W2,
                                            const ushort_t* __restrict__ mask)
{
  const float* sq = (const float*)(ws + OFF_SQ);
  const float* sk = (const float*)(ws + OFF_SK);
  ushort_t* watt = (ushort_t*)(ws + OFF_WATT);
  const int dtf = *(const int*)(ws + OFF_DTYPE);
  int tid = threadIdx.x; int wv = tid>>6, l = tid&63;
  int bq = blockIdx.x*4 + wv;
  int b  = bq >> 8;
  float sqv[10], w2v[10];
  #pragma unroll
  for (int x=0;x<10;++x){ sqv[x] = sq[(size_t)bq*10+x]; w2v[x] = loadS(W2, x, dtf); }
  float a[4];
  #pragma unroll
  for (int kk=0;kk<4;++kk){
    int k = kk*64 + l;
    const float* skp = sk + ((size_t)b*256 + k)*10;
    float s = 0.f;
    #pragma unroll
    for (int x=0;x<10;++x) s += tanh_f(sqv[x] + skp[x]) * w2v[x];
    float mval = loadS(mask, (size_t)b*256 + k, dtf);
    a[kk] = (mval == 0.f) ? -1e30f : s;
  }
  float mx = fmaxf(fmaxf(a[0],a[1]), fmaxf(a[2],a[3]));
  #pragma unroll
  for (int off=32; off>0; off>>=1) mx = fmaxf(mx, __shfl_xor(mx, off, 64));
  float e[4], ssum=0.f;
  #pragma unroll
  for (int kk=0;kk<4;++kk){ e[kk] = __expf(a[kk]-mx); ssum += e[kk]; }
  #pragma unroll
  for (int off=32; off>0; off>>=1) ssum += __shfl_xor(ssum, off, 64);
  float inv = 1.f/ssum;
  #pragma unroll
  for (int kk=0;kk<4;++kk) watt[(size_t)bq*256 + kk*64 + l] = f2b(e[kk]*inv);
}

// =====================================================================
extern "C" void kernel_launch(void* const* d_in, const int* in_sizes, int n_in,
                              void* d_out, int out_size, void* d_ws, size_t ws_size,
                              hipStream_t stream)
{
  const ushort_t* x     = (const ushort_t*)d_in[0];
  const ushort_t* mask  = (const ushort_t*)d_in[1];
  const ushort_t* Wih_f = (const ushort_t*)d_in[2];
  const ushort_t* Whh_f = (const ushort_t*)d_in[3];
  const ushort_t* b_f   = (const ushort_t*)d_in[4];
  const ushort_t* Wih_b = (const ushort_t*)d_in[5];
  const ushort_t* Whh_b = (const ushort_t*)d_in[6];
  const ushort_t* b_b   = (const ushort_t*)d_in[7];
  const ushort_t* W1    = (const ushort_t*)d_in[8];
  const ushort_t* W2    = (const ushort_t*)d_in[9];
  const ushort_t* W3    = (const ushort_t*)d_in[10];
  const ushort_t* b3    = (const ushort_t*)d_in[11];
  ushort_t* out = (ushort_t*)d_out;
  char* ws = (char*)d_ws;

  const bool conc = ws_size >= (size_t)NEED_CONC;
  ushort_t* hist = (ushort_t*)(ws + OFF_XZ + (conc ? 33554432u : 16777216u));

  hipMemsetAsync(ws, 0, 4096, stream);           // dtype flag + barrier flags
  detect_k<<<dim3(1), dim3(256), 0, stream>>>((const uint32_t*)d_in[0], ws);

  dim3 blk(256);
  if (conc){
    gemm_k<0><<<dim3(64,8,1), blk, 0, stream>>>(x, nullptr, Wih_f, b_f, nullptr, ws,
                                                DB_, DB_, DB_, 0, 1, 1, 0,0, 0L);
    gemm_k<0><<<dim3(64,8,1), blk, 0, stream>>>(x, nullptr, Wih_b, b_b, nullptr, ws,
                                                DB_, DB_, DB_, 1, 1, 1, 0,0, (long)XZ_DIR_ELEMS);
    rec_k<<<dim3(16), blk, 0, stream>>>(Whh_f, Whh_b, ws, hist, 0, (long)XZ_DIR_ELEMS);
  } else {
    gemm_k<0><<<dim3(64,8,1), blk, 0, stream>>>(x, nullptr, Wih_f, b_f, nullptr, ws,
                                                DB_, DB_, DB_, 0, 1, 1, 0,0, 0L);
    rec_k<<<dim3(8), blk, 0, stream>>>(Whh_f, Whh_b, ws, hist, 0, 0L);
    gemm_k<0><<<dim3(64,8,1), blk, 0, stream>>>(x, nullptr, Wih_b, b_b, nullptr, ws,
                                                DB_, DB_, DB_, 1, 1, 1, 0,0, 0L);
    rec_k<<<dim3(8), blk, 0, stream>>>(Whh_f, Whh_b, ws, hist, 1, 0L);
  }
  // attention
  c1_k<<<dim3(2048), blk, 0, stream>>>(ws, W1, hist);
  c2_k<<<dim3(2048), blk, 0, stream>>>(ws, W2, mask);
  // context = watt @ h (per batch), B row-major from hist
  gemm_k<3><<<dim3(2,4,32), blk, 0, stream>>>((ushort_t*)(ws+OFF_WATT), nullptr,
                                              hist, nullptr,
                                              (ushort_t*)(ws+OFF_CTX), ws,
                                              256, 512, 256, 0, 0, 0,
                                              65536L, 131072L, 131072L);
  // y = concat(h, ctx) @ W3^T + b3 -> d_out (dtype-matched store)
  gemm_k<2><<<dim3(64,4,1), blk, 0, stream>>>(hist, (ushort_t*)(ws+OFF_CTX),
                                              W3, b3, out, ws,
                                              512, 1024, 1024, 0, 0, 1, 0,0, 0L);
}

// Round 9
// 1358.936 us; speedup vs baseline: 2.7213x; 1.0597x over previous
//
#include <hip/hip_runtime.h>
#include <stdint.h>

// ---------------- problem constants ----------------
#define B_   32
#define T_   256
#define H_   256      // per-direction hidden
#define DB_  768      // input dim
#define DL_  512      // 2*H

// ---------------- workspace layout (bytes) ----------------
#define OFF_DTYPE 0u                          // int: 1 = inputs bf16, 0 = f32
#define OFF_FLAGS 256u                        // [2 dir][256 t] u32 flag counters (target 8)
#define OFF_HBUF  4096u                       // [2 parity][2 dir][32 b][128 u32] = 64 KB
#define OFF_XZ    69632u                      // swizzled xz, per-dir stride 8M elems (16 MB)
#define XZ_DIR_ELEMS 8388608u
#define NEED_CONC (OFF_XZ + 2u*16777216u + 8388608u)
// ---- aliased into the xz region (xz dead after rec) ----
#define OFF_CTX   OFF_XZ                      // context [32][256][512] bf16 = 8 MB
#define OFF_WATT  (OFF_XZ + 8388608u)         // attn weights [32][256][256] bf16 = 4 MB
#define OFF_SQ    (OFF_XZ + 12582912u)        // [8192][10] f32
#define OFF_SK    (OFF_SQ + 327680u)          // [8192][10] f32

typedef __attribute__((ext_vector_type(8))) short bf16x8;
typedef __attribute__((ext_vector_type(4))) float f32x4;
typedef __attribute__((ext_vector_type(4))) uint32_t u32x4;
typedef unsigned short ushort_t;

__device__ __forceinline__ float b2f(ushort_t u){ union{float f; uint32_t i;} v; v.i=((uint32_t)u)<<16; return v.f; }
__device__ __forceinline__ ushort_t f2b(float f){
  union{float ff; uint32_t i;} v; v.ff=f;
  uint32_t r = v.i + 0x7fffu + ((v.i>>16)&1u);
  return (ushort_t)(r>>16);
}
__device__ __forceinline__ float sig_f(float x){ return 1.f/(1.f+__expf(-x)); }
__device__ __forceinline__ float tanh_f(float x){ return 1.f - 2.f/(1.f+__expf(2.f*x)); }

__device__ __forceinline__ bf16x8 load8(const ushort_t* p, size_t idx, int isbf){
  if (isbf) return *(const bf16x8*)(p + idx);
  const float* f = (const float*)p;
  bf16x8 r;
  #pragma unroll
  for (int i=0;i<8;++i) r[i] = (short)f2b(f[idx+i]);
  return r;
}
__device__ __forceinline__ float loadS(const ushort_t* p, size_t idx, int isbf){
  return isbf ? b2f(p[idx]) : ((const float*)p)[idx];
}

// =====================================================================
// dtype probe (R3-verified): votes f32 vs bf16 from exponent stats.
// =====================================================================
__global__ void detect_k(const uint32_t* __restrict__ x, char* __restrict__ ws){
  __shared__ int cnt;
  if (threadIdx.x == 0) cnt = 0;
  __syncthreads();
  int local = 0;
  #pragma unroll
  for (int i=0;i<4;++i){
    uint32_t w = x[threadIdx.x*4 + i];
    uint32_t lo = w & 0xFFFFu;
    int e = (int)((lo >> 7) & 0xFFu);
    if (e >= 118 && e <= 130) local++;
  }
  atomicAdd(&cnt, local);
  __syncthreads();
  if (threadIdx.x == 0) *(int*)(ws + OFF_DTYPE) = (cnt > 512) ? 1 : 0;
}

// =====================================================================
// Generic 128x128-tile bf16 MFMA GEMM (unchanged, R4-R8-verified).
// =====================================================================
template<int MODE>
__global__ __launch_bounds__(256,2) void gemm_k(
    const ushort_t* __restrict__ A0, const ushort_t* __restrict__ A2,
    const ushort_t* __restrict__ Bm, const ushort_t* __restrict__ bias,
    ushort_t* __restrict__ Cout, char* __restrict__ ws,
    int lda, int ldb, int K, int dir, int aIn, int bIn,
    long aOffZ, long bOffZ, long cOffZ)
{
  __shared__ ushort_t As[8192];
  __shared__ ushort_t Bs[8192];
  const int dtf = *(const int*)(ws + OFF_DTYPE);
  const int aBF = aIn ? dtf : 1;
  const int bBF = bIn ? dtf : 1;
  const int tid = threadIdx.x;
  const int l  = tid & 63, wv = tid >> 6;
  const int lc = l & 15,  lh = l >> 4;
  const int m0 = blockIdx.x * 128, n0 = blockIdx.y * 128;
  const int z  = blockIdx.z;
  const ushort_t* Abase = A0 + (size_t)z * aOffZ;
  const ushort_t* Bbase = Bm + (size_t)z * bOffZ;
  const int srow = tid >> 3;
  const int sch  = tid & 7;

  f32x4 acc[4][4];
  #pragma unroll
  for (int i=0;i<4;++i)
    #pragma unroll
    for (int j=0;j<4;++j) acc[i][j] = (f32x4){0.f,0.f,0.f,0.f};

  bf16x8 ra[4], rb[4];
  #pragma unroll
  for (int p=0;p<4;++p){
    int row = p*32 + srow;
    int kk  = (sch ^ (row & 7)) * 8;
    ra[p] = load8(Abase, (size_t)(m0+row)*lda + kk, aBF);
    if (MODE==3){
      int q = p*256 + tid, kr = q>>4, c = q&15;
      rb[p] = load8(Bbase, (size_t)kr*ldb + n0 + c*8, 1);
    } else {
      rb[p] = load8(Bbase, (size_t)(n0+row)*ldb + kk, bBF);
    }
  }

  const int mo = (wv&1)*64, no = (wv>>1)*64;

  for (int k0 = 0; k0 < K; k0 += 64) {
    #pragma unroll
    for (int p=0;p<4;++p){
      int row = p*32 + srow;
      *(bf16x8*)(&As[row*64 + sch*8]) = ra[p];
      if (MODE==3){
        int q = p*256 + tid, kr = q>>4, c = q&15;
        *(bf16x8*)(&Bs[kr*128 + c*8]) = rb[p];
      } else {
        *(bf16x8*)(&Bs[row*64 + sch*8]) = rb[p];
      }
    }
    __syncthreads();
    int k1 = k0 + 64;
    if (k1 < K) {
      #pragma unroll
      for (int p=0;p<4;++p){
        int row = p*32 + srow;
        int kk  = k1 + (sch ^ (row & 7)) * 8;
        if (MODE==2 && k1 >= 512)
          ra[p] = load8(A2, (size_t)(m0+row)*512 + (kk - 512), 1);
        else
          ra[p] = load8(Abase, (size_t)(m0+row)*lda + kk, aBF);
        if (MODE==3){
          int q = p*256 + tid, kr = q>>4, c = q&15;
          rb[p] = load8(Bbase, (size_t)(k1+kr)*ldb + n0 + c*8, 1);
        } else {
          rb[p] = load8(Bbase, (size_t)(n0+row)*ldb + kk, bBF);
        }
      }
    }
    #pragma unroll
    for (int kc=0;kc<2;++kc){
      bf16x8 af[4], bfv[4];
      #pragma unroll
      for (int it=0;it<4;++it){
        int m = mo + it*16 + lc;
        int gc = kc*4 + lh;
        af[it]  = *(const bf16x8*)(&As[m*64 + ((gc ^ (m&7))*8)]);
        int n = no + it*16 + lc;
        if (MODE==3){
          #pragma unroll
          for (int j=0;j<8;++j) bfv[it][j] = (short)Bs[(kc*32 + lh*8 + j)*128 + n];
        } else {
          bfv[it] = *(const bf16x8*)(&Bs[n*64 + ((gc ^ (n&7))*8)]);
        }
      }
      #pragma unroll
      for (int mt=0;mt<4;++mt)
        #pragma unroll
        for (int nt=0;nt<4;++nt)
          acc[mt][nt] = __builtin_amdgcn_mfma_f32_16x16x32_bf16(af[mt], bfv[nt], acc[mt][nt], 0,0,0);
    }
    __syncthreads();
  }

  ushort_t* xzsw = (ushort_t*)(ws + OFF_XZ);
  #pragma unroll
  for (int mt=0;mt<4;++mt){
    #pragma unroll
    for (int nt=0;nt<4;++nt){
      #pragma unroll
      for (int r=0;r<4;++r){
        int m = m0 + mo + mt*16 + lh*4 + r;
        int n = n0 + no + nt*16 + lc;
        float v = acc[mt][nt][r];
        if (MODE==0){
          v += loadS(bias, n, bBF);
          int b = m >> 8, t = m & 255;
          int ts = dir ? (255 - t) : t;
          int q = n >> 8, jm = n & 255;
          int w = jm >> 6, jj = jm & 63, wvv = jj >> 4, colj = jj & 15;
          int lane = ((b >> 2) & 3)*16 + colj;
          int idx  = (b >> 4)*16 + q*4 + (b & 3);
          size_t e = (((size_t)(w*4 + wvv)*256 + ts)*2048) + (size_t)lane*32 + idx;
          xzsw[e + (size_t)cOffZ] = f2b(v);
        } else if (MODE==3){
          Cout[(size_t)z*cOffZ + (size_t)m*DL_ + n] = f2b(v);
        } else {
          v += loadS(bias, n, bBF);
          if (dtf) Cout[(size_t)m*DL_ + n] = f2b(v);
          else     ((float*)Cout)[(size_t)m*DL_ + n] = v;
        }
      }
    }
  }
}

// =====================================================================
// Persistent BiLSTM recurrence, v5 — NO per-step cache invalidation.
// Weights in 64 KB static LDS (R8-proven). h handoff:
//   producer: relaxed agent u32 stores (LLC) + packed u32 hist stores ->
//   waitcnt -> barrier -> 1 flag RMW/block (agent LLC, target 8).
//   consumer: tid0 relaxed poll -> barrier -> 8 PLAIN buffer_load_dwordx4
//   with CPol sc0|sc1 (bypass L1/L2, read LLC, fully pipelined,
//   compiler-managed vmcnt) -> ds_read weights + 32 MFMA -> cell.
// No fences: reader L1/L2 never cache hbuf; xz/L2 stays warm.
// =====================================================================
__global__ __launch_bounds__(256,1) void rec_k(
    const ushort_t* __restrict__ Whh_f, const ushort_t* __restrict__ Whh_b,
    char* __restrict__ ws, ushort_t* __restrict__ hist,
    int dParam, long xzDirStride)
{
  __shared__ ushort_t wlds[32768];   // 64 KB: 64 frags x 1 KB
  const int d  = (gridDim.x == 16) ? (int)(blockIdx.x >> 3) : dParam;
  const int bw = (int)(blockIdx.x & 7);
  const int tid = threadIdx.x;
  const int wv = tid >> 6, l = tid & 63;
  const int lc = l & 15, lh = l >> 4;
  const int bh = wv & 1, hh = wv >> 1;
  const int dtf = *(const int*)(ws + OFF_DTYPE);

  uint32_t* flags = (uint32_t*)(ws + OFF_FLAGS);
  uint32_t* hbuf  = (uint32_t*)(ws + OFF_HBUF);     // u32-packed bf16 pairs
  const ushort_t* xz = (const ushort_t*)(ws + OFF_XZ) + (size_t)d * xzDirStride;
  const ushort_t* Whh = d ? Whh_b : Whh_f;

  const int jj = bw*32 + hh*16 + lc;    // this lane's hidden unit
  const int g  = bw*2 + hh;             // hidden-16-group for xz layout

  // ---- stage this block's 64 KB weight slice into LDS (R8-proven) ----
  #pragma unroll
  for (int i=0;i<16;++i){
    int f   = wv*16 + i;
    int fhh = f >> 5, fnt = (f >> 3) & 3, fkc = f & 7;
    int row = fnt*256 + bw*32 + fhh*16 + lc;
    bf16x8 v = load8(Whh, (size_t)row*256 + fkc*32 + lh*8, dtf);
    *(bf16x8*)(&wlds[f*512 + l*8]) = v;
  }
  __syncthreads();
  const int wbase = (hh*4)*8;   // this wave's fragment group base

  float cst[4] = {0.f, 0.f, 0.f, 0.f};

  const ushort_t* xzb = xz + (size_t)g*256*2048 + (size_t)l*32 + bh*16;
  const int hOffByte = (bh*16 + lc)*512 + lh*16;   // per-lane h-load base (bytes)

  for (int t=0; t<T_; ++t){
    // prefetch xz[t] (plain cached loads — L2 stays warm, no invalidates)
    bf16x8 xzv[2];
    xzv[0] = *(const bf16x8*)(xzb + (size_t)t*2048);
    xzv[1] = *(const bf16x8*)(xzb + (size_t)t*2048 + 8);

    f32x4 acc[4];
    #pragma unroll
    for (int j=0;j<4;++j) acc[j] = (f32x4){0.f,0.f,0.f,0.f};

    if (t > 0){
      if (tid == 0){
        const uint32_t* fl = flags + d*T_ + (t-1);
        while (__hip_atomic_load(fl, __ATOMIC_RELAXED, __HIP_MEMORY_SCOPE_AGENT) < 8u) {}
      }
      __syncthreads();

      const uint32_t* hb = hbuf + (size_t)(((t-1)&1)*2 + d)*(B_*H_/2);
      __amdgpu_buffer_rsrc_t rs =
        __builtin_amdgcn_make_buffer_rsrc((void*)hb, (short)0, 0xFFFFFFFFu, 0x00020000);
      u32x4 hreg[8];
      #pragma unroll
      for (int kc=0;kc<8;++kc)
        hreg[kc] = __builtin_bit_cast(u32x4,
          __builtin_amdgcn_raw_buffer_load_b128(rs, hOffByte + kc*64, 0, /*sc0|sc1*/17));

      #pragma unroll
      for (int kc=0;kc<8;++kc){
        bf16x8 a = __builtin_bit_cast(bf16x8, hreg[kc]);
        #pragma unroll
        for (int nt=0;nt<4;++nt){
          bf16x8 wfrag = *(const bf16x8*)(&wlds[(wbase + nt*8 + kc)*512 + l*8]);
          acc[nt] = __builtin_amdgcn_mfma_f32_16x16x32_bf16(a, wfrag, acc[nt], 0,0,0);
        }
      }
    }

    const int ts = d ? (255 - t) : t;
    uint32_t* hb_out = hbuf + (size_t)((t&1)*2 + d)*(B_*H_/2);
    uint32_t* histw  = (uint32_t*)hist;
    #pragma unroll
    for (int r=0;r<4;++r){
      float zi = acc[0][r] + b2f((ushort_t)xzv[(r+0 )>>3][(r+0 )&7]);
      float zf = acc[1][r] + b2f((ushort_t)xzv[(r+4 )>>3][(r+4 )&7]);
      float zg = acc[2][r] + b2f((ushort_t)xzv[(r+8 )>>3][(r+8 )&7]);
      float zo = acc[3][r] + b2f((ushort_t)xzv[(r+12)>>3][(r+12)&7]);
      float ig = sig_f(zi), fg = sig_f(zf), gg = tanh_f(zg), og = sig_f(zo);
      float c = fg * cst[r] + ig * gg;
      cst[r] = c;
      float h = og * tanh_f(c);
      ushort_t h16 = f2b(h);
      int b = bh*16 + lh*4 + r;
      uint32_t mine = (uint32_t)h16;
      uint32_t partner = (uint32_t)__shfl_xor((int)mine, 1);
      if ((lc & 1) == 0){
        uint32_t packed = mine | (partner << 16);
        __hip_atomic_store(hb_out + (size_t)b*128 + (jj>>1), packed,
                           __ATOMIC_RELAXED, __HIP_MEMORY_SCOPE_AGENT);
        histw[(((size_t)(b*256 + ts))*512 + d*256 + jj) >> 1] = packed;  // plain cached
      }
    }
    __builtin_amdgcn_s_waitcnt(0);   // drain stores before flagging
    __syncthreads();
    if (tid == 0)
      __hip_atomic_fetch_add(flags + d*T_ + t, 1u, __ATOMIC_RELAXED, __HIP_MEMORY_SCOPE_AGENT);
  }
}

// =====================================================================
// C1: sq[m][x] = h[m]·W1[x][0:512], sk[m][x] = h[m]·W1[x][512:1024]
// =====================================================================
__global__ __launch_bounds__(256) void c1_k(char* __restrict__ ws, const ushort_t* __restrict__ W1,
                                            const ushort_t* __restrict__ hist)
{
  float* sq = (float*)(ws + OFF_SQ);
  float* sk = (float*)(ws + OFF_SK);
  const int dtf = *(const int*)(ws + OFF_DTYPE);
  int tid = threadIdx.x; int wv = tid>>6, l = tid&63;
  int row = blockIdx.x*4 + wv;
  bf16x8 hv = *(const bf16x8*)(hist + (size_t)row*512 + l*8);
  float hf[8];
  #pragma unroll
  for (int i=0;i<8;++i) hf[i] = b2f((ushort_t)hv[i]);
  #pragma unroll
  for (int x=0;x<10;++x){
    bf16x8 qv = load8(W1, (size_t)x*1024 + l*8, dtf);
    bf16x8 kv = load8(W1, (size_t)x*1024 + 512 + l*8, dtf);
    float pq=0.f, pk=0.f;
    #pragma unroll
    for (int i=0;i<8;++i){ pq += hf[i]*b2f((ushort_t)qv[i]); pk += hf[i]*b2f((ushort_t)kv[i]); }
    #pragma unroll
    for (int off=32; off>0; off>>=1){ pq += __shfl_xor(pq, off, 64); pk += __shfl_xor(pk, off, 64); }
    if (l == 0){ sq[row*10 + x] = pq; sk[row*10 + x] = pk; }
  }
}

// =====================================================================
// C2: a = sum_x tanh(sq+sk)*W2[x]; masked softmax -> bf16 watt
// =====================================================================
__global__ __launch_bounds__(256) void c2_k(char* __restrict__ ws, const ushort_t* __restrict__ W2,
                                            const ushort_t* __restrict__ mask)
{
  const float* sq = (const float*)(ws + OFF_SQ);
  const float* sk = (const float*)(ws + OFF_SK);
  ushort_t* watt = (ushort_t*)(ws + OFF_WATT);
  const int dtf = *(const int*)(ws + OFF_DTYPE);
  int tid = threadIdx.x; int wv = tid>>6, l = tid&63;
  int bq = blockIdx.x*4 + wv;
  int b  = bq >> 8;
  float sqv[10], w2v[10];
  #pragma unroll
  for (int x=0;x<10;++x){ sqv[x] = sq[(size_t)bq*10+x]; w2v[x] = loadS(W2, x, dtf); }
  float a[4];
  #pragma unroll
  for (int kk=0;kk<4;++kk){
    int k = kk*64 + l;
    const float* skp = sk + ((size_t)b*256 + k)*10;
    float s = 0.f;
    #pragma unroll
    for (int x=0;x<10;++x) s += tanh_f(sqv[x] + skp[x]) * w2v[x];
    float mval = loadS(mask, (size_t)b*256 + k, dtf);
    a[kk] = (mval == 0.f) ? -1e30f : s;
  }
  float mx = fmaxf(fmaxf(a[0],a[1]), fmaxf(a[2],a[3]));
  #pragma unroll
  for (int off=32; off>0; off>>=1) mx = fmaxf(mx, __shfl_xor(mx, off, 64));
  float e[4], ssum=0.f;
  #pragma unroll
  for (int kk=0;kk<4;++kk){ e[kk] = __expf(a[kk]-mx); ssum += e[kk]; }
  #pragma unroll
  for (int off=32; off>0; off>>=1) ssum += __shfl_xor(ssum, off, 64);
  float inv = 1.f/ssum;
  #pragma unroll
  for (int kk=0;kk<4;++kk) watt[(size_t)bq*256 + kk*64 + l] = f2b(e[kk]*inv);
}

// =====================================================================
extern "C" void kernel_launch(void* const* d_in, const int* in_sizes, int n_in,
                              void* d_out, int out_size, void* d_ws, size_t ws_size,
                              hipStream_t stream)
{
  const ushort_t* x     = (const ushort_t*)d_in[0];
  const ushort_t* mask  = (const ushort_t*)d_in[1];
  const ushort_t* Wih_f = (const ushort_t*)d_in[2];
  const ushort_t* Whh_f = (const ushort_t*)d_in[3];
  const ushort_t* b_f   = (const ushort_t*)d_in[4];
  const ushort_t* Wih_b = (const ushort_t*)d_in[5];
  const ushort_t* Whh_b = (const ushort_t*)d_in[6];
  const ushort_t* b_b   = (const ushort_t*)d_in[7];
  const ushort_t* W1    = (const ushort_t*)d_in[8];
  const ushort_t* W2    = (const ushort_t*)d_in[9];
  const ushort_t* W3    = (const ushort_t*)d_in[10];
  const ushort_t* b3    = (const ushort_t*)d_in[11];
  ushort_t* out = (ushort_t*)d_out;
  char* ws = (char*)d_ws;

  const bool conc = ws_size >= (size_t)NEED_CONC;
  ushort_t* hist = (ushort_t*)(ws + OFF_XZ + (conc ? 33554432u : 16777216u));

  hipMemsetAsync(ws, 0, 4096, stream);           // dtype flag + barrier flags
  detect_k<<<dim3(1), dim3(256), 0, stream>>>((const uint32_t*)d_in[0], ws);

  dim3 blk(256);
  if (conc){
    gemm_k<0><<<dim3(64,8,1), blk, 0, stream>>>(x, nullptr, Wih_f, b_f, nullptr, ws,
                                                DB_, DB_, DB_, 0, 1, 1, 0,0, 0L);
    gemm_k<0><<<dim3(64,8,1), blk, 0, stream>>>(x, nullptr, Wih_b, b_b, nullptr, ws,
                                                DB_, DB_, DB_, 1, 1, 1, 0,0, (long)XZ_DIR_ELEMS);
    rec_k<<<dim3(16), blk, 0, stream>>>(Whh_f, Whh_b, ws, hist, 0, (long)XZ_DIR_ELEMS);
  } else {
    gemm_k<0><<<dim3(64,8,1), blk, 0, stream>>>(x, nullptr, Wih_f, b_f, nullptr, ws,
                                                DB_, DB_, DB_, 0, 1, 1, 0,0, 0L);
    rec_k<<<dim3(8), blk, 0, stream>>>(Whh_f, Whh_b, ws, hist, 0, 0L);
    gemm_k<0><<<dim3(64,8,1), blk, 0, stream>>>(x, nullptr, Wih_b, b_b, nullptr, ws,
                                                DB_, DB_, DB_, 1, 1, 1, 0,0, 0L);
    rec_k<<<dim3(8), blk, 0, stream>>>(Whh_f, Whh_b, ws, hist, 1, 0L);
  }
  // attention
  c1_k<<<dim3(2048), blk, 0, stream>>>(ws, W1, hist);
  c2_k<<<dim3(2048), blk, 0, stream>>>(ws, W2, mask);
  // context = watt @ h (per batch), B row-major from hist
  gemm_k<3><<<dim3(2,4,32), blk, 0, stream>>>((ushort_t*)(ws+OFF_WATT), nullptr,
                                              hist, nullptr,
                                              (ushort_t*)(ws+OFF_CTX), ws,
                                              256, 512, 256, 0, 0, 0,
                                              65536L, 131072L, 131072L);
  // y = concat(h, ctx) @ W3^T + b3 -> d_out (dtype-matched store)
  gemm_k<2><<<dim3(64,4,1), blk, 0, stream>>>(hist, (ushort_t*)(ws+OFF_CTX),
                                              W3, b3, out, ws,
                                              512, 1024, 1024, 0, 0, 1, 0,0, 0L);
}